// Round 2
// baseline (1705.483 us; speedup 1.0000x reference)
//
#include <hip/hip_runtime.h>
#include <hip/hip_bf16.h>

// ---------------------------------------------------------------------------
// LSTM_net: 6x biLSTM(H=8, T=4) + conv/deconv/fc head, B=131072. All f32.
//  - one thread per batch element; all state in registers; f32 compute
//  - prep1: repack LSTM weights into d_ws (biases combined)
//  - prep2: pre-compose the affine conv/deconv/fc head into M[16x64]+b[16]
//  - main:  LSTM layers fully unrolled, head = 16x64 dense affine + tanh
// Weights are wave-uniform -> expect s_load via scalar cache (verify in disasm).
// ---------------------------------------------------------------------------

#define OFF_WIH0 0      // [2][32][2]   = 128
#define OFF_WHH0 128    // [2][32][8]   = 512
#define OFF_B0   640    // [2][32]      = 64   (b_ih0 + b_hh0)
#define OFF_WIH  704    // [5][2][32][16] = 5120
#define OFF_WHH  5824   // [5][2][32][8]  = 2560
#define OFF_B    8384   // [5][2][32]     = 640 (b_ih + b_hh)
#define OFF_M    9024   // [16][64]       = 1024 (composed conv head, linear part)
#define OFF_MB   10048  // [16]           = 16   (composed conv head, bias)
// total 10064 floats = 40256 bytes of d_ws

__device__ __forceinline__ float sigm(float x) { return 1.0f / (1.0f + __expf(-x)); }
__device__ __forceinline__ float tanhx(float x) { return 1.0f - 2.0f / (__expf(2.0f * x) + 1.0f); }

// ---------------------------------------------------------------------------
// prep1: repack f32 LSTM weights, combine biases
// ---------------------------------------------------------------------------
__global__ __launch_bounds__(256) void prep_lstm_w(
    const float* __restrict__ wih0, const float* __restrict__ whh0,
    const float* __restrict__ bih0, const float* __restrict__ bhh0,
    const float* __restrict__ wih,  const float* __restrict__ whh,
    const float* __restrict__ bih,  const float* __restrict__ bhh,
    float* __restrict__ W)
{
    int tid = blockIdx.x * blockDim.x + threadIdx.x;
    int n = gridDim.x * blockDim.x;
    for (int i = tid; i < 128; i += n)  W[OFF_WIH0 + i] = wih0[i];
    for (int i = tid; i < 512; i += n)  W[OFF_WHH0 + i] = whh0[i];
    for (int i = tid; i < 64; i += n)   W[OFF_B0 + i] = bih0[i] + bhh0[i];
    for (int i = tid; i < 5120; i += n) W[OFF_WIH + i] = wih[i];
    for (int i = tid; i < 2560; i += n) W[OFF_WHH + i] = whh[i];
    for (int i = tid; i < 640; i += n)  W[OFF_B + i] = bih[i] + bhh[i];
}

// ---------------------------------------------------------------------------
// prep2: compose conv1->conv2->deconv1->deconv2->fc1->fc2 (all affine in the
// post-sigmoid s[64]) into out_pre = M[16x64]*s + Mb[16].
// 65 columns (64 basis + 1 bias column); 5 blocks x 13 columns, stages in LDS.
// ---------------------------------------------------------------------------
__global__ __launch_bounds__(256) void prep_conv_mat(
    const float* __restrict__ c1w, const float* __restrict__ c1b,
    const float* __restrict__ c2w, const float* __restrict__ c2b,
    const float* __restrict__ d1w, const float* __restrict__ d1b,
    const float* __restrict__ d2w, const float* __restrict__ d2b,
    const float* __restrict__ f1w, const float* __restrict__ f1b,
    const float* __restrict__ f2w, const float* __restrict__ f2b,
    float* __restrict__ W)
{
    __shared__ float A[13][232];
    __shared__ float Bf[13][232];
    const int tid = threadIdx.x;
    const int base = blockIdx.x * 13;

    // init: columns of identity (col 64 = zero vector -> pure bias propagation)
    for (int idx = tid; idx < 13 * 64; idx += 256) {
        int cl = idx / 64, r = idx % 64;
        A[cl][r] = (base + cl == r) ? 1.0f : 0.0f;
    }
    __syncthreads();
    // conv1: s[4][16] -> c1[8][15]
    for (int idx = tid; idx < 13 * 120; idx += 256) {
        int cl = idx / 120, rr = idx % 120; int o = rr / 15, l = rr % 15;
        float acc = (base + cl == 64) ? c1b[o] : 0.0f;
        for (int i = 0; i < 4; i++)
            for (int kk = 0; kk < 2; kk++)
                acc += c1w[(o * 4 + i) * 2 + kk] * A[cl][i * 16 + l + kk];
        Bf[cl][rr] = acc;
    }
    __syncthreads();
    // conv2: c1[8][15] -> c2[16][14]
    for (int idx = tid; idx < 13 * 224; idx += 256) {
        int cl = idx / 224, rr = idx % 224; int o = rr / 14, l = rr % 14;
        float acc = (base + cl == 64) ? c2b[o] : 0.0f;
        for (int i = 0; i < 8; i++)
            for (int kk = 0; kk < 2; kk++)
                acc += c2w[(o * 8 + i) * 2 + kk] * Bf[cl][i * 15 + l + kk];
        A[cl][rr] = acc;
    }
    __syncthreads();
    // deconv1 (w [16][8][2]): c2[16][14] -> d1[8][15]
    for (int idx = tid; idx < 13 * 120; idx += 256) {
        int cl = idx / 120, rr = idx % 120; int o = rr / 15, l = rr % 15;
        float acc = (base + cl == 64) ? d1b[o] : 0.0f;
        for (int i = 0; i < 16; i++)
            for (int kk = 0; kk < 2; kk++) {
                int ls = l - kk;
                if (ls >= 0 && ls < 14)
                    acc += d1w[(i * 8 + o) * 2 + kk] * A[cl][i * 14 + ls];
            }
        Bf[cl][rr] = acc;
    }
    __syncthreads();
    // deconv2 (w [8][4][2]): d1[8][15] -> d2[4][16]
    for (int idx = tid; idx < 13 * 64; idx += 256) {
        int cl = idx / 64, rr = idx % 64; int o = rr / 16, l = rr % 16;
        float acc = (base + cl == 64) ? d2b[o] : 0.0f;
        for (int i = 0; i < 8; i++)
            for (int kk = 0; kk < 2; kk++) {
                int ls = l - kk;
                if (ls >= 0 && ls < 15)
                    acc += d2w[(i * 4 + o) * 2 + kk] * Bf[cl][i * 15 + ls];
            }
        A[cl][rr] = acc;
    }
    __syncthreads();
    // fc1 (w [8][16], contracts length dim): d2[4][16] -> f1[4][8]
    for (int idx = tid; idx < 13 * 32; idx += 256) {
        int cl = idx / 32, rr = idx % 32; int ch = rr / 8, jj = rr % 8;
        float acc = (base + cl == 64) ? f1b[jj] : 0.0f;
        for (int l = 0; l < 16; l++)
            acc += f1w[jj * 16 + l] * A[cl][ch * 16 + l];
        Bf[cl][rr] = acc;
    }
    __syncthreads();
    // fc2 (w [4][8]): f1[4][8] -> out_pre[4][4]; write M / Mb
    for (int idx = tid; idx < 13 * 16; idx += 256) {
        int cl = idx / 16, rr = idx % 16; int ch = rr / 4, m = rr % 4;
        int col = base + cl;
        if (col > 64) continue;
        float acc = (col == 64) ? f2b[m] : 0.0f;
        for (int j = 0; j < 8; j++)
            acc += f2w[m * 8 + j] * Bf[cl][ch * 8 + j];
        if (col < 64) W[OFF_M + rr * 64 + col] = acc;
        else          W[OFF_MB + rr] = acc;
    }
}

// ---------------------------------------------------------------------------
// main kernel
// ---------------------------------------------------------------------------
__device__ __forceinline__ void load8(const float* __restrict__ p, float (&d)[8]) {
    float4 v0 = *reinterpret_cast<const float4*>(p);
    float4 v1 = *reinterpret_cast<const float4*>(p + 4);
    d[0] = v0.x; d[1] = v0.y; d[2] = v0.z; d[3] = v0.w;
    d[4] = v1.x; d[5] = v1.y; d[6] = v1.z; d[7] = v1.w;
}

template<int DIN>
__device__ __forceinline__ void lstm_step(const float (&xin)[DIN], float (&h)[8], float (&c)[8],
    const float* __restrict__ wih, const float* __restrict__ whh, const float* __restrict__ bias)
{
    float hn[8];
#pragma unroll
    for (int u = 0; u < 8; ++u) {
        float ai = bias[u], af = bias[8 + u], ag = bias[16 + u], ao = bias[24 + u];
#pragma unroll
        for (int k = 0; k < DIN; ++k) {
            float xv = xin[k];
            ai = fmaf(xv, wih[u * DIN + k], ai);
            af = fmaf(xv, wih[(8 + u) * DIN + k], af);
            ag = fmaf(xv, wih[(16 + u) * DIN + k], ag);
            ao = fmaf(xv, wih[(24 + u) * DIN + k], ao);
        }
#pragma unroll
        for (int k = 0; k < 8; ++k) {
            float hv = h[k];
            ai = fmaf(hv, whh[u * 8 + k], ai);
            af = fmaf(hv, whh[(8 + u) * 8 + k], af);
            ag = fmaf(hv, whh[(16 + u) * 8 + k], ag);
            ao = fmaf(hv, whh[(24 + u) * 8 + k], ao);
        }
        float cn = sigm(af) * c[u] + sigm(ai) * tanhx(ag);
        c[u] = cn;
        hn[u] = sigm(ao) * tanhx(cn);
    }
#pragma unroll
    for (int u = 0; u < 8; ++u) h[u] = hn[u];
}

__global__ __launch_bounds__(256, 2) void lstm_main(
    const float* __restrict__ x, const float* __restrict__ h0,
    const float* __restrict__ c0, const float* __restrict__ W,
    float* __restrict__ out, int B)
{
    int b = blockIdx.x * 256 + threadIdx.x;
    if (b >= B) return;

    float y[4][16];
    float xin[4][2];
    {
        float4 v0 = *reinterpret_cast<const float4*>(x + (size_t)b * 8);
        float4 v1 = *reinterpret_cast<const float4*>(x + (size_t)b * 8 + 4);
        xin[0][0] = v0.x; xin[0][1] = v0.y; xin[1][0] = v0.z; xin[1][1] = v0.w;
        xin[2][0] = v1.x; xin[2][1] = v1.y; xin[3][0] = v1.z; xin[3][1] = v1.w;
    }
    // ---- layer 0 (Din=2), slots 0 (fwd) / 1 (bwd) ----
    {
        float h[8], c[8], hf[4][8];
        load8(h0 + ((size_t)0 * B + b) * 8, h);
        load8(c0 + ((size_t)0 * B + b) * 8, c);
#pragma unroll
        for (int t = 0; t < 4; t++) {
            lstm_step<2>(xin[t], h, c, W + OFF_WIH0, W + OFF_WHH0, W + OFF_B0);
#pragma unroll
            for (int k = 0; k < 8; k++) hf[t][k] = h[k];
        }
        load8(h0 + ((size_t)1 * B + b) * 8, h);
        load8(c0 + ((size_t)1 * B + b) * 8, c);
#pragma unroll
        for (int tt = 0; tt < 4; tt++) {
            const int t = 3 - tt;
            lstm_step<2>(xin[t], h, c, W + OFF_WIH0 + 64, W + OFF_WHH0 + 256, W + OFF_B0 + 32);
#pragma unroll
            for (int k = 0; k < 8; k++) { y[t][k] = hf[t][k]; y[t][8 + k] = h[k]; }
        }
    }
    // ---- layers 1..5 (Din=16), slots 2l / 2l+1 ----
    for (int l = 0; l < 5; l++) {
        const float* wf = W + OFF_WIH + l * 1024;
        const float* uf = W + OFF_WHH + l * 512;
        const float* bf = W + OFF_B + l * 64;
        const int slot = 2 * (l + 1);
        float h[8], c[8], hf[4][8];
        load8(h0 + ((size_t)slot * B + b) * 8, h);
        load8(c0 + ((size_t)slot * B + b) * 8, c);
#pragma unroll
        for (int t = 0; t < 4; t++) {
            lstm_step<16>(y[t], h, c, wf, uf, bf);
#pragma unroll
            for (int k = 0; k < 8; k++) hf[t][k] = h[k];
        }
        load8(h0 + ((size_t)(slot + 1) * B + b) * 8, h);
        load8(c0 + ((size_t)(slot + 1) * B + b) * 8, c);
#pragma unroll
        for (int tt = 0; tt < 4; tt++) {
            const int t = 3 - tt;
            lstm_step<16>(y[t], h, c, wf + 512, uf + 256, bf + 32);
#pragma unroll
            for (int k = 0; k < 8; k++) { y[t][k] = hf[t][k]; y[t][8 + k] = h[k]; }
        }
    }
    // ---- head: sigmoid, composed affine map, tanh ----
    float s[64];
#pragma unroll
    for (int t = 0; t < 4; t++)
#pragma unroll
        for (int j = 0; j < 16; j++) s[t * 16 + j] = sigm(y[t][j]);

    float o16[16];
#pragma unroll
    for (int o = 0; o < 16; o++) {
        float acc = W[OFF_MB + o];
#pragma unroll
        for (int j = 0; j < 64; j++) acc = fmaf(W[OFF_M + o * 64 + j], s[j], acc);
        o16[o] = tanhx(acc);
    }
    float4* op = reinterpret_cast<float4*>(out + (size_t)b * 16);
    op[0] = make_float4(o16[0], o16[1], o16[2], o16[3]);
    op[1] = make_float4(o16[4], o16[5], o16[6], o16[7]);
    op[2] = make_float4(o16[8], o16[9], o16[10], o16[11]);
    op[3] = make_float4(o16[12], o16[13], o16[14], o16[15]);
}

extern "C" void kernel_launch(void* const* d_in, const int* in_sizes, int n_in,
                              void* d_out, int out_size, void* d_ws, size_t ws_size,
                              hipStream_t stream)
{
    const float* x    = (const float*)d_in[0];
    const float* h0   = (const float*)d_in[1];
    const float* c0   = (const float*)d_in[2];
    const float* wih0 = (const float*)d_in[3];
    const float* whh0 = (const float*)d_in[4];
    const float* bih0 = (const float*)d_in[5];
    const float* bhh0 = (const float*)d_in[6];
    const float* wih  = (const float*)d_in[7];
    const float* whh  = (const float*)d_in[8];
    const float* bih  = (const float*)d_in[9];
    const float* bhh  = (const float*)d_in[10];
    const float* c1w  = (const float*)d_in[11];
    const float* c1b  = (const float*)d_in[12];
    const float* c2w  = (const float*)d_in[13];
    const float* c2b  = (const float*)d_in[14];
    const float* d1w  = (const float*)d_in[15];
    const float* d1b  = (const float*)d_in[16];
    const float* d2w  = (const float*)d_in[17];
    const float* d2b  = (const float*)d_in[18];
    const float* f1w  = (const float*)d_in[19];
    const float* f1b  = (const float*)d_in[20];
    const float* f2w  = (const float*)d_in[21];
    const float* f2b  = (const float*)d_in[22];

    float* W = (float*)d_ws;
    const int B = in_sizes[0] / 8;

    prep_lstm_w<<<36, 256, 0, stream>>>(wih0, whh0, bih0, bhh0, wih, whh, bih, bhh, W);
    prep_conv_mat<<<5, 256, 0, stream>>>(c1w, c1b, c2w, c2b, d1w, d1b, d2w, d2b,
                                         f1w, f1b, f2w, f2b, W);
    lstm_main<<<(B + 255) / 256, 256, 0, stream>>>(x, h0, c0, W, (float*)d_out, B);
}

// Round 3
// 522.488 us; speedup vs baseline: 3.2642x; 3.2642x over previous
//
#include <hip/hip_runtime.h>
#include <hip/hip_bf16.h>

// ---------------------------------------------------------------------------
// LSTM_net: 6x biLSTM(H=8, T=4) + composed affine head, B=131072. All f32.
// Round 2 restructure: 8 lanes per batch element, lane = LSTM unit.
//  - each lane holds ALL FOUR gate rows (i,f,g,o) of its unit in VGPRs
//    -> zero per-FMA memory traffic, gate->c->h update fully lane-local
//  - only cross-lane op: broadcast h[8] per step = 8 ds_bpermute per wave
//    (serves 8 elements at once)
//  - waves = B/8 = 16384 (vs 2048 before): occupancy no longer grid-capped
//  - head fused: sigmoid + M[16x64] affine + tanh, s transposed through LDS
// ---------------------------------------------------------------------------

#define OFF_WIH0 0      // [2][32][2]   = 128
#define OFF_WHH0 128    // [2][32][8]   = 512
#define OFF_B0   640    // [2][32]      = 64   (b_ih0 + b_hh0)
#define OFF_WIH  704    // [5][2][32][16] = 5120
#define OFF_WHH  5824   // [5][2][32][8]  = 2560
#define OFF_B    8384   // [5][2][32]     = 640 (b_ih + b_hh)
#define OFF_M    9024   // [16][64]       = 1024 (composed conv head, linear part)
#define OFF_MB   10048  // [16]           = 16   (composed conv head, bias)

__device__ __forceinline__ float rcpf_(float x) {
#if __has_builtin(__builtin_amdgcn_rcpf)
    return __builtin_amdgcn_rcpf(x);
#else
    return 1.0f / x;
#endif
}
__device__ __forceinline__ float exp2f_(float x) {
#if __has_builtin(__builtin_amdgcn_exp2f)
    return __builtin_amdgcn_exp2f(x);
#else
    return exp2f(x);
#endif
}
__device__ __forceinline__ float sigm(float x) {
    return rcpf_(1.0f + exp2f_(-1.44269504f * x));
}
__device__ __forceinline__ float tanhx(float x) {
    return fmaf(2.0f, rcpf_(1.0f + exp2f_(-2.88539008f * x)), -1.0f);
}

// ---------------------------------------------------------------------------
// prep1: repack f32 LSTM weights, combine biases (unchanged layout)
// ---------------------------------------------------------------------------
__global__ __launch_bounds__(256) void prep_lstm_w(
    const float* __restrict__ wih0, const float* __restrict__ whh0,
    const float* __restrict__ bih0, const float* __restrict__ bhh0,
    const float* __restrict__ wih,  const float* __restrict__ whh,
    const float* __restrict__ bih,  const float* __restrict__ bhh,
    float* __restrict__ W)
{
    int tid = blockIdx.x * blockDim.x + threadIdx.x;
    int n = gridDim.x * blockDim.x;
    for (int i = tid; i < 128; i += n)  W[OFF_WIH0 + i] = wih0[i];
    for (int i = tid; i < 512; i += n)  W[OFF_WHH0 + i] = whh0[i];
    for (int i = tid; i < 64; i += n)   W[OFF_B0 + i] = bih0[i] + bhh0[i];
    for (int i = tid; i < 5120; i += n) W[OFF_WIH + i] = wih[i];
    for (int i = tid; i < 2560; i += n) W[OFF_WHH + i] = whh[i];
    for (int i = tid; i < 640; i += n)  W[OFF_B + i] = bih[i] + bhh[i];
}

// ---------------------------------------------------------------------------
// prep2: compose conv1->conv2->deconv1->deconv2->fc1->fc2 into M[16x64]+Mb[16]
// (unchanged from round 1 — verified correct)
// ---------------------------------------------------------------------------
__global__ __launch_bounds__(256) void prep_conv_mat(
    const float* __restrict__ c1w, const float* __restrict__ c1b,
    const float* __restrict__ c2w, const float* __restrict__ c2b,
    const float* __restrict__ d1w, const float* __restrict__ d1b,
    const float* __restrict__ d2w, const float* __restrict__ d2b,
    const float* __restrict__ f1w, const float* __restrict__ f1b,
    const float* __restrict__ f2w, const float* __restrict__ f2b,
    float* __restrict__ W)
{
    __shared__ float A[13][232];
    __shared__ float Bf[13][232];
    const int tid = threadIdx.x;
    const int base = blockIdx.x * 13;

    for (int idx = tid; idx < 13 * 64; idx += 256) {
        int cl = idx / 64, r = idx % 64;
        A[cl][r] = (base + cl == r) ? 1.0f : 0.0f;
    }
    __syncthreads();
    for (int idx = tid; idx < 13 * 120; idx += 256) {
        int cl = idx / 120, rr = idx % 120; int o = rr / 15, l = rr % 15;
        float acc = (base + cl == 64) ? c1b[o] : 0.0f;
        for (int i = 0; i < 4; i++)
            for (int kk = 0; kk < 2; kk++)
                acc += c1w[(o * 4 + i) * 2 + kk] * A[cl][i * 16 + l + kk];
        Bf[cl][rr] = acc;
    }
    __syncthreads();
    for (int idx = tid; idx < 13 * 224; idx += 256) {
        int cl = idx / 224, rr = idx % 224; int o = rr / 14, l = rr % 14;
        float acc = (base + cl == 64) ? c2b[o] : 0.0f;
        for (int i = 0; i < 8; i++)
            for (int kk = 0; kk < 2; kk++)
                acc += c2w[(o * 8 + i) * 2 + kk] * Bf[cl][i * 15 + l + kk];
        A[cl][rr] = acc;
    }
    __syncthreads();
    for (int idx = tid; idx < 13 * 120; idx += 256) {
        int cl = idx / 120, rr = idx % 120; int o = rr / 15, l = rr % 15;
        float acc = (base + cl == 64) ? d1b[o] : 0.0f;
        for (int i = 0; i < 16; i++)
            for (int kk = 0; kk < 2; kk++) {
                int ls = l - kk;
                if (ls >= 0 && ls < 14)
                    acc += d1w[(i * 8 + o) * 2 + kk] * A[cl][i * 14 + ls];
            }
        Bf[cl][rr] = acc;
    }
    __syncthreads();
    for (int idx = tid; idx < 13 * 64; idx += 256) {
        int cl = idx / 64, rr = idx % 64; int o = rr / 16, l = rr % 16;
        float acc = (base + cl == 64) ? d2b[o] : 0.0f;
        for (int i = 0; i < 8; i++)
            for (int kk = 0; kk < 2; kk++) {
                int ls = l - kk;
                if (ls >= 0 && ls < 15)
                    acc += d2w[(i * 4 + o) * 2 + kk] * Bf[cl][i * 15 + ls];
            }
        A[cl][rr] = acc;
    }
    __syncthreads();
    for (int idx = tid; idx < 13 * 32; idx += 256) {
        int cl = idx / 32, rr = idx % 32; int ch = rr / 8, jj = rr % 8;
        float acc = (base + cl == 64) ? f1b[jj] : 0.0f;
        for (int l = 0; l < 16; l++)
            acc += f1w[jj * 16 + l] * A[cl][ch * 16 + l];
        Bf[cl][rr] = acc;
    }
    __syncthreads();
    for (int idx = tid; idx < 13 * 16; idx += 256) {
        int cl = idx / 16, rr = idx % 16; int ch = rr / 4, m = rr % 4;
        int col = base + cl;
        if (col > 64) continue;
        float acc = (col == 64) ? f2b[m] : 0.0f;
        for (int j = 0; j < 8; j++)
            acc += f2w[m * 8 + j] * Bf[cl][ch * 8 + j];
        if (col < 64) W[OFF_M + rr * 64 + col] = acc;
        else          W[OFF_MB + rr] = acc;
    }
}

// ---------------------------------------------------------------------------
// one biLSTM direction, Din=16. Lane owns unit u: rows {u, u+8, u+16, u+24}.
// IL/IH: input halves (replicated across the 8 lanes of the elem).
// OUT[t] receives the broadcast h (all 8 lanes get all 8 units' h).
// ---------------------------------------------------------------------------
template<bool FWD>
__device__ __forceinline__ void run16(
    const float* __restrict__ wih, const float* __restrict__ whh,
    const float* __restrict__ bias,
    const float* __restrict__ h0e, const float* __restrict__ c0e,
    int u, int bbase,
    const float (&IL)[4][8], const float (&IH)[4][8],
    float (&OUT)[4][8])
{
    float wi[4][16], wh[4][8], bs[4];
#pragma unroll
    for (int g = 0; g < 4; g++) {
        const int r = u + 8 * g;
        const float4* wr = reinterpret_cast<const float4*>(wih + r * 16);
        float4 v0 = wr[0], v1 = wr[1], v2 = wr[2], v3 = wr[3];
        wi[g][0] = v0.x; wi[g][1] = v0.y; wi[g][2] = v0.z; wi[g][3] = v0.w;
        wi[g][4] = v1.x; wi[g][5] = v1.y; wi[g][6] = v1.z; wi[g][7] = v1.w;
        wi[g][8] = v2.x; wi[g][9] = v2.y; wi[g][10] = v2.z; wi[g][11] = v2.w;
        wi[g][12] = v3.x; wi[g][13] = v3.y; wi[g][14] = v3.z; wi[g][15] = v3.w;
        const float4* ur = reinterpret_cast<const float4*>(whh + r * 8);
        float4 u0 = ur[0], u1 = ur[1];
        wh[g][0] = u0.x; wh[g][1] = u0.y; wh[g][2] = u0.z; wh[g][3] = u0.w;
        wh[g][4] = u1.x; wh[g][5] = u1.y; wh[g][6] = u1.z; wh[g][7] = u1.w;
        bs[g] = bias[r];
    }
    float hinit[8];
    {
        const float4* hp = reinterpret_cast<const float4*>(h0e);
        float4 a = hp[0], b = hp[1];
        hinit[0] = a.x; hinit[1] = a.y; hinit[2] = a.z; hinit[3] = a.w;
        hinit[4] = b.x; hinit[5] = b.y; hinit[6] = b.z; hinit[7] = b.w;
    }
    float cc = c0e[u];

    auto step = [&](int t, const float (&hin)[8]) {
        float g4[4];
#pragma unroll
        for (int g = 0; g < 4; g++) {
            float a = bs[g];
#pragma unroll
            for (int k = 0; k < 8; k++) a = fmaf(IL[t][k], wi[g][k], a);
#pragma unroll
            for (int k = 0; k < 8; k++) a = fmaf(IH[t][k], wi[g][8 + k], a);
#pragma unroll
            for (int k = 0; k < 8; k++) a = fmaf(hin[k], wh[g][k], a);
            g4[g] = a;
        }
        float si = sigm(g4[0]), sf = sigm(g4[1]);
        float tg = tanhx(g4[2]), so = sigm(g4[3]);
        cc = fmaf(sf, cc, si * tg);
        float hn = so * tanhx(cc);
#pragma unroll
        for (int k = 0; k < 8; k++)
            OUT[t][k] = __int_as_float(
                __builtin_amdgcn_ds_bpermute(bbase + 4 * k, __float_as_int(hn)));
    };
    if (FWD) { step(0, hinit); step(1, OUT[0]); step(2, OUT[1]); step(3, OUT[2]); }
    else     { step(3, hinit); step(2, OUT[3]); step(1, OUT[2]); step(0, OUT[1]); }
}

// same for layer 0 (Din=2)
template<bool FWD>
__device__ __forceinline__ void run2(
    const float* __restrict__ wih, const float* __restrict__ whh,
    const float* __restrict__ bias,
    const float* __restrict__ h0e, const float* __restrict__ c0e,
    int u, int bbase,
    const float (&xin)[4][2],
    float (&OUT)[4][8])
{
    float wi[4][2], wh[4][8], bs[4];
#pragma unroll
    for (int g = 0; g < 4; g++) {
        const int r = u + 8 * g;
        const float2* wr = reinterpret_cast<const float2*>(wih + r * 2);
        float2 v = wr[0];
        wi[g][0] = v.x; wi[g][1] = v.y;
        const float4* ur = reinterpret_cast<const float4*>(whh + r * 8);
        float4 u0 = ur[0], u1 = ur[1];
        wh[g][0] = u0.x; wh[g][1] = u0.y; wh[g][2] = u0.z; wh[g][3] = u0.w;
        wh[g][4] = u1.x; wh[g][5] = u1.y; wh[g][6] = u1.z; wh[g][7] = u1.w;
        bs[g] = bias[r];
    }
    float hinit[8];
    {
        const float4* hp = reinterpret_cast<const float4*>(h0e);
        float4 a = hp[0], b = hp[1];
        hinit[0] = a.x; hinit[1] = a.y; hinit[2] = a.z; hinit[3] = a.w;
        hinit[4] = b.x; hinit[5] = b.y; hinit[6] = b.z; hinit[7] = b.w;
    }
    float cc = c0e[u];

    auto step = [&](int t, const float (&hin)[8]) {
        float g4[4];
#pragma unroll
        for (int g = 0; g < 4; g++) {
            float a = bs[g];
            a = fmaf(xin[t][0], wi[g][0], a);
            a = fmaf(xin[t][1], wi[g][1], a);
#pragma unroll
            for (int k = 0; k < 8; k++) a = fmaf(hin[k], wh[g][k], a);
            g4[g] = a;
        }
        float si = sigm(g4[0]), sf = sigm(g4[1]);
        float tg = tanhx(g4[2]), so = sigm(g4[3]);
        cc = fmaf(sf, cc, si * tg);
        float hn = so * tanhx(cc);
#pragma unroll
        for (int k = 0; k < 8; k++)
            OUT[t][k] = __int_as_float(
                __builtin_amdgcn_ds_bpermute(bbase + 4 * k, __float_as_int(hn)));
    };
    if (FWD) { step(0, hinit); step(1, OUT[0]); step(2, OUT[1]); step(3, OUT[2]); }
    else     { step(3, hinit); step(2, OUT[3]); step(1, OUT[2]); step(0, OUT[1]); }
}

// ---------------------------------------------------------------------------
// main kernel: block = 256 threads = 4 waves = 32 batch elements
// ---------------------------------------------------------------------------
__global__ __launch_bounds__(256, 2) void lstm_main(
    const float* __restrict__ x, const float* __restrict__ h0,
    const float* __restrict__ c0, const float* __restrict__ W,
    float* __restrict__ out, int B)
{
    __shared__ float sbuf[32 * 64];   // per-elem s[64] staging for the head
    const int tid = threadIdx.x;
    const int lane = tid & 63;
    const int u = lane & 7;                 // LSTM unit owned by this lane
    const int elemLocal = tid >> 3;         // 0..31
    const int elem = blockIdx.x * 32 + elemLocal;
    const int bbase = (lane & 56) << 2;     // bpermute byte base of elem group

    float xin[4][2];
    {
        const float4* xp = reinterpret_cast<const float4*>(x + (size_t)elem * 8);
        float4 a = xp[0], b = xp[1];
        xin[0][0] = a.x; xin[0][1] = a.y; xin[1][0] = a.z; xin[1][1] = a.w;
        xin[2][0] = b.x; xin[2][1] = b.y; xin[3][0] = b.z; xin[3][1] = b.w;
    }

    float XL[4][8], XH[4][8], TMP[4][8];

    // ---- layer 0: bwd -> XH, fwd -> XL ----
    run2<false>(W + OFF_WIH0 + 64, W + OFF_WHH0 + 256, W + OFF_B0 + 32,
                h0 + ((size_t)1 * B + elem) * 8, c0 + ((size_t)1 * B + elem) * 8,
                u, bbase, xin, XH);
    run2<true>(W + OFF_WIH0, W + OFF_WHH0, W + OFF_B0,
               h0 + ((size_t)0 * B + elem) * 8, c0 + ((size_t)0 * B + elem) * 8,
               u, bbase, xin, XL);

    // ---- layers 1..5: bwd (reads XL,XH) -> TMP; fwd overwrites XL in place;
    //      then XH <- TMP ----
    for (int l = 0; l < 5; l++) {
        const float* wi = W + OFF_WIH + (size_t)(l * 2) * 512;
        const float* wh = W + OFF_WHH + (size_t)(l * 2) * 256;
        const float* bb = W + OFF_B + (size_t)(l * 2) * 32;
        const int slot = 2 * l + 2;
        run16<false>(wi + 512, wh + 256, bb + 32,
                     h0 + ((size_t)(slot + 1) * B + elem) * 8,
                     c0 + ((size_t)(slot + 1) * B + elem) * 8,
                     u, bbase, XL, XH, TMP);
        run16<true>(wi, wh, bb,
                    h0 + ((size_t)slot * B + elem) * 8,
                    c0 + ((size_t)slot * B + elem) * 8,
                    u, bbase, XL, XH, XL);
#pragma unroll
        for (int t = 0; t < 4; t++)
#pragma unroll
            for (int k = 0; k < 8; k++) XH[t][k] = TMP[t][k];
    }

    // ---- head: sigmoid -> LDS transpose -> M[16x64] affine -> tanh ----
    // lane u covers s indices j in [8u, 8u+8): row order
    // u=0:XL[0] u=1:XH[0] u=2:XL[1] u=3:XH[1] u=4:XL[2] u=5:XH[2] u=6:XL[3] u=7:XH[3]
    {
        const bool b0 = (u & 1), b1 = (u & 2), b2 = (u & 4);
        float* sb = sbuf + elemLocal * 64;
#pragma unroll
        for (int m = 0; m < 8; m++) {
            float v01 = b0 ? XH[0][m] : XL[0][m];
            float v23 = b0 ? XH[1][m] : XL[1][m];
            float v45 = b0 ? XH[2][m] : XL[2][m];
            float v67 = b0 ? XH[3][m] : XL[3][m];
            float w0 = b1 ? v23 : v01;
            float w1 = b1 ? v67 : v45;
            float val = b2 ? w1 : w0;
            sb[8 * u + m] = sigm(val);
        }
        // same-wave producer/consumer: lgkmcnt handled by compiler, no barrier
        const int o0 = 2 * u, o1 = 2 * u + 1;
        const float* M0 = W + OFF_M + o0 * 64;
        const float* M1 = W + OFF_M + o1 * 64;
        float acc0 = W[OFF_MB + o0];
        float acc1 = W[OFF_MB + o1];
#pragma unroll
        for (int q = 0; q < 16; q++) {
            const float4 sv = *reinterpret_cast<const float4*>(sb + 4 * q);
            const float4 m0 = *reinterpret_cast<const float4*>(M0 + 4 * q);
            const float4 m1 = *reinterpret_cast<const float4*>(M1 + 4 * q);
            acc0 = fmaf(sv.x, m0.x, acc0); acc0 = fmaf(sv.y, m0.y, acc0);
            acc0 = fmaf(sv.z, m0.z, acc0); acc0 = fmaf(sv.w, m0.w, acc0);
            acc1 = fmaf(sv.x, m1.x, acc1); acc1 = fmaf(sv.y, m1.y, acc1);
            acc1 = fmaf(sv.z, m1.z, acc1); acc1 = fmaf(sv.w, m1.w, acc1);
        }
        float2 res;
        res.x = tanhx(acc0);
        res.y = tanhx(acc1);
        *reinterpret_cast<float2*>(out + (size_t)elem * 16 + 2 * u) = res;
    }
}

extern "C" void kernel_launch(void* const* d_in, const int* in_sizes, int n_in,
                              void* d_out, int out_size, void* d_ws, size_t ws_size,
                              hipStream_t stream)
{
    const float* x    = (const float*)d_in[0];
    const float* h0   = (const float*)d_in[1];
    const float* c0   = (const float*)d_in[2];
    const float* wih0 = (const float*)d_in[3];
    const float* whh0 = (const float*)d_in[4];
    const float* bih0 = (const float*)d_in[5];
    const float* bhh0 = (const float*)d_in[6];
    const float* wih  = (const float*)d_in[7];
    const float* whh  = (const float*)d_in[8];
    const float* bih  = (const float*)d_in[9];
    const float* bhh  = (const float*)d_in[10];
    const float* c1w  = (const float*)d_in[11];
    const float* c1b  = (const float*)d_in[12];
    const float* c2w  = (const float*)d_in[13];
    const float* c2b  = (const float*)d_in[14];
    const float* d1w  = (const float*)d_in[15];
    const float* d1b  = (const float*)d_in[16];
    const float* d2w  = (const float*)d_in[17];
    const float* d2b  = (const float*)d_in[18];
    const float* f1w  = (const float*)d_in[19];
    const float* f1b  = (const float*)d_in[20];
    const float* f2w  = (const float*)d_in[21];
    const float* f2b  = (const float*)d_in[22];

    float* W = (float*)d_ws;
    const int B = in_sizes[0] / 8;

    prep_lstm_w<<<36, 256, 0, stream>>>(wih0, whh0, bih0, bhh0, wih, whh, bih, bhh, W);
    prep_conv_mat<<<5, 256, 0, stream>>>(c1w, c1b, c2w, c2b, d1w, d1b, d2w, d2b,
                                         f1w, f1b, f2w, f2b, W);
    lstm_main<<<B / 32, 256, 0, stream>>>(x, h0, c0, W, (float*)d_out, B);
}

// Round 4
// 440.243 us; speedup vs baseline: 3.8740x; 1.1868x over previous
//
#include <hip/hip_runtime.h>
#include <hip/hip_bf16.h>

// ---------------------------------------------------------------------------
// LSTM_net: 6x biLSTM(H=8, T=4) + composed affine head, B=131072. All f32.
// Round 4: fix round-3's weight-reload stall (VGPR=88, VALUBusy 47%).
//  - lane = (elem%8, unit): each lane owns all 4 gate rows of its unit
//  - weights loaded ONCE per layer-dir and PINNED in VGPRs via asm ("+v")
//    -> compiler cannot rematerialize the loads inside the recurrence
//  - layer activations live in LDS ping-pong (stride 68: conflict-free),
//    not registers -> pressure drops ~96 regs; no barriers (same-wave)
//  - gate FMAs as f32x2 + elementwise_fma -> v_pk_fma_f32 candidates
//  - layer 5 stores sigm(h); head reads LDS + L1-hot M[16x64]
// ---------------------------------------------------------------------------

using f32x2 = __attribute__((ext_vector_type(2))) float;
using f32x4 = __attribute__((ext_vector_type(4))) float;

#define OFF_WIH0 0      // [2][32][2]   = 128
#define OFF_WHH0 128    // [2][32][8]   = 512
#define OFF_B0   640    // [2][32]      = 64   (b_ih0 + b_hh0)
#define OFF_WIH  704    // [5][2][32][16] = 5120
#define OFF_WHH  5824   // [5][2][32][8]  = 2560
#define OFF_B    8384   // [5][2][32]     = 640 (b_ih + b_hh)
#define OFF_M    9024   // [16][64]       = 1024 (composed conv head, linear)
#define OFF_MB   10048  // [16]           = 16   (composed conv head, bias)

__device__ __forceinline__ float rcpf_(float x) {
#if __has_builtin(__builtin_amdgcn_rcpf)
    return __builtin_amdgcn_rcpf(x);
#else
    return 1.0f / x;
#endif
}
__device__ __forceinline__ float exp2f_(float x) {
#if __has_builtin(__builtin_amdgcn_exp2f)
    return __builtin_amdgcn_exp2f(x);
#else
    return exp2f(x);
#endif
}
__device__ __forceinline__ float sigm(float x) {
    return rcpf_(1.0f + exp2f_(-1.44269504f * x));
}
__device__ __forceinline__ float tanhx(float x) {
    return fmaf(2.0f, rcpf_(1.0f + exp2f_(-2.88539008f * x)), -1.0f);
}

// ---------------------------------------------------------------------------
// prep (fused): blocks 0..35 repack LSTM weights; blocks 36..40 compose the
// affine conv/deconv/fc head into M[16x64] + Mb[16].
// ---------------------------------------------------------------------------
__global__ __launch_bounds__(256) void prep_all(
    const float* __restrict__ wih0, const float* __restrict__ whh0,
    const float* __restrict__ bih0, const float* __restrict__ bhh0,
    const float* __restrict__ wih,  const float* __restrict__ whh,
    const float* __restrict__ bih,  const float* __restrict__ bhh,
    const float* __restrict__ c1w, const float* __restrict__ c1b,
    const float* __restrict__ c2w, const float* __restrict__ c2b,
    const float* __restrict__ d1w, const float* __restrict__ d1b,
    const float* __restrict__ d2w, const float* __restrict__ d2b,
    const float* __restrict__ f1w, const float* __restrict__ f1b,
    const float* __restrict__ f2w, const float* __restrict__ f2b,
    float* __restrict__ W)
{
    __shared__ float A[13][232];
    __shared__ float Bf[13][232];
    const int tid = threadIdx.x;

    if (blockIdx.x < 36) {
        int t = blockIdx.x * 256 + tid;
        const int n = 36 * 256;
        for (int i = t; i < 128; i += n)  W[OFF_WIH0 + i] = wih0[i];
        for (int i = t; i < 512; i += n)  W[OFF_WHH0 + i] = whh0[i];
        for (int i = t; i < 64; i += n)   W[OFF_B0 + i] = bih0[i] + bhh0[i];
        for (int i = t; i < 5120; i += n) W[OFF_WIH + i] = wih[i];
        for (int i = t; i < 2560; i += n) W[OFF_WHH + i] = whh[i];
        for (int i = t; i < 640; i += n)  W[OFF_B + i] = bih[i] + bhh[i];
        return;
    }
    const int base = (blockIdx.x - 36) * 13;

    for (int idx = tid; idx < 13 * 64; idx += 256) {
        int cl = idx / 64, r = idx % 64;
        A[cl][r] = (base + cl == r) ? 1.0f : 0.0f;
    }
    __syncthreads();
    for (int idx = tid; idx < 13 * 120; idx += 256) {
        int cl = idx / 120, rr = idx % 120; int o = rr / 15, l = rr % 15;
        float acc = (base + cl == 64) ? c1b[o] : 0.0f;
        for (int i = 0; i < 4; i++)
            for (int kk = 0; kk < 2; kk++)
                acc += c1w[(o * 4 + i) * 2 + kk] * A[cl][i * 16 + l + kk];
        Bf[cl][rr] = acc;
    }
    __syncthreads();
    for (int idx = tid; idx < 13 * 224; idx += 256) {
        int cl = idx / 224, rr = idx % 224; int o = rr / 14, l = rr % 14;
        float acc = (base + cl == 64) ? c2b[o] : 0.0f;
        for (int i = 0; i < 8; i++)
            for (int kk = 0; kk < 2; kk++)
                acc += c2w[(o * 8 + i) * 2 + kk] * Bf[cl][i * 15 + l + kk];
        A[cl][rr] = acc;
    }
    __syncthreads();
    for (int idx = tid; idx < 13 * 120; idx += 256) {
        int cl = idx / 120, rr = idx % 120; int o = rr / 15, l = rr % 15;
        float acc = (base + cl == 64) ? d1b[o] : 0.0f;
        for (int i = 0; i < 16; i++)
            for (int kk = 0; kk < 2; kk++) {
                int ls = l - kk;
                if (ls >= 0 && ls < 14)
                    acc += d1w[(i * 8 + o) * 2 + kk] * A[cl][i * 14 + ls];
            }
        Bf[cl][rr] = acc;
    }
    __syncthreads();
    for (int idx = tid; idx < 13 * 64; idx += 256) {
        int cl = idx / 64, rr = idx % 64; int o = rr / 16, l = rr % 16;
        float acc = (base + cl == 64) ? d2b[o] : 0.0f;
        for (int i = 0; i < 8; i++)
            for (int kk = 0; kk < 2; kk++) {
                int ls = l - kk;
                if (ls >= 0 && ls < 15)
                    acc += d2w[(i * 4 + o) * 2 + kk] * Bf[cl][i * 15 + ls];
            }
        A[cl][rr] = acc;
    }
    __syncthreads();
    for (int idx = tid; idx < 13 * 32; idx += 256) {
        int cl = idx / 32, rr = idx % 32; int ch = rr / 8, jj = rr % 8;
        float acc = (base + cl == 64) ? f1b[jj] : 0.0f;
        for (int l = 0; l < 16; l++)
            acc += f1w[jj * 16 + l] * A[cl][ch * 16 + l];
        Bf[cl][rr] = acc;
    }
    __syncthreads();
    for (int idx = tid; idx < 13 * 16; idx += 256) {
        int cl = idx / 16, rr = idx % 16; int ch = rr / 4, m = rr % 4;
        int col = base + cl;
        if (col > 64) continue;
        float acc = (col == 64) ? f2b[m] : 0.0f;
        for (int j = 0; j < 8; j++)
            acc += f2w[m * 8 + j] * Bf[cl][ch * 8 + j];
        if (col < 64) W[OFF_M + rr * 64 + col] = acc;
        else          W[OFF_MB + rr] = acc;
    }
}

// ---------------------------------------------------------------------------
// one layer-direction, Din=16. lin/lout: this elem's 68-float LDS rows.
// ---------------------------------------------------------------------------
template<bool FWD>
__device__ __forceinline__ void layer16(
    const float* __restrict__ Wi, const float* __restrict__ Wh,
    const float* __restrict__ Bs,
    const float* __restrict__ h0e, const float* __restrict__ c0e,
    int u, int bbase, const float* lin, float* lout, bool last)
{
    f32x4 wiv[4][4];   // 4 gates x 16 input weights
    f32x4 whv[4][2];   // 4 gates x 8 hidden weights
    f32x4 bsv;
#pragma unroll
    for (int g = 0; g < 4; g++) {
        const int r = u + 8 * g;
        const f32x4* wr = reinterpret_cast<const f32x4*>(Wi + r * 16);
        wiv[g][0] = wr[0]; wiv[g][1] = wr[1]; wiv[g][2] = wr[2]; wiv[g][3] = wr[3];
        const f32x4* ur = reinterpret_cast<const f32x4*>(Wh + r * 8);
        whv[g][0] = ur[0]; whv[g][1] = ur[1];
        bsv[g] = Bs[r];
    }
    // pin: make weight values opaque so they cannot be reloaded per-step
#pragma unroll
    for (int g = 0; g < 4; g++) {
        asm volatile("" : "+v"(wiv[g][0]), "+v"(wiv[g][1]),
                          "+v"(wiv[g][2]), "+v"(wiv[g][3]));
        asm volatile("" : "+v"(whv[g][0]), "+v"(whv[g][1]));
    }
    asm volatile("" : "+v"(bsv));

    float hin[8];
    {
        const f32x4* hp = reinterpret_cast<const f32x4*>(h0e);
        f32x4 a = hp[0], b = hp[1];
        hin[0] = a.x; hin[1] = a.y; hin[2] = a.z; hin[3] = a.w;
        hin[4] = b.x; hin[5] = b.y; hin[6] = b.z; hin[7] = b.w;
    }
    float cc = c0e[u];

#pragma unroll
    for (int s = 0; s < 4; s++) {
        const int t = FWD ? s : 3 - s;
        const f32x4* ip = reinterpret_cast<const f32x4*>(lin + 16 * t);
        f32x4 i0 = ip[0], i1 = ip[1], i2 = ip[2], i3 = ip[3];
        f32x2 xin[8];
        xin[0] = f32x2{i0.x, i0.y}; xin[1] = f32x2{i0.z, i0.w};
        xin[2] = f32x2{i1.x, i1.y}; xin[3] = f32x2{i1.z, i1.w};
        xin[4] = f32x2{i2.x, i2.y}; xin[5] = f32x2{i2.z, i2.w};
        xin[6] = f32x2{i3.x, i3.y}; xin[7] = f32x2{i3.z, i3.w};
        f32x2 acc[4];
#pragma unroll
        for (int g = 0; g < 4; g++) acc[g] = f32x2{bsv[g], 0.0f};
#pragma unroll
        for (int g = 0; g < 4; g++) {
#pragma unroll
            for (int j = 0; j < 4; j++) {
                f32x2 wlo = f32x2{wiv[g][j].x, wiv[g][j].y};
                f32x2 whi = f32x2{wiv[g][j].z, wiv[g][j].w};
                acc[g] = __builtin_elementwise_fma(xin[2 * j], wlo, acc[g]);
                acc[g] = __builtin_elementwise_fma(xin[2 * j + 1], whi, acc[g]);
            }
#pragma unroll
            for (int j = 0; j < 2; j++) {
                f32x2 wlo = f32x2{whv[g][j].x, whv[g][j].y};
                f32x2 whi = f32x2{whv[g][j].z, whv[g][j].w};
                f32x2 h0p = f32x2{hin[4 * j], hin[4 * j + 1]};
                f32x2 h1p = f32x2{hin[4 * j + 2], hin[4 * j + 3]};
                acc[g] = __builtin_elementwise_fma(h0p, wlo, acc[g]);
                acc[g] = __builtin_elementwise_fma(h1p, whi, acc[g]);
            }
        }
        float si = sigm(acc[0].x + acc[0].y);
        float sf = sigm(acc[1].x + acc[1].y);
        float tg = tanhx(acc[2].x + acc[2].y);
        float so = sigm(acc[3].x + acc[3].y);
        cc = fmaf(sf, cc, si * tg);
        float hn = so * tanhx(cc);
#pragma unroll
        for (int k = 0; k < 8; k++)
            hin[k] = __int_as_float(
                __builtin_amdgcn_ds_bpermute(bbase + 4 * k, __float_as_int(hn)));
        float st = last ? sigm(hn) : hn;
        lout[16 * t + (FWD ? 0 : 8) + u] = st;
    }
}

// layer 0 (Din=2), input in registers
template<bool FWD>
__device__ __forceinline__ void layer2(
    const float* __restrict__ Wi, const float* __restrict__ Wh,
    const float* __restrict__ Bs,
    const float* __restrict__ h0e, const float* __restrict__ c0e,
    int u, int bbase, const f32x2 (&xin2)[4], float* lout)
{
    f32x2 wiv[4];
    f32x4 whv[4][2];
    f32x4 bsv;
#pragma unroll
    for (int g = 0; g < 4; g++) {
        const int r = u + 8 * g;
        wiv[g] = *reinterpret_cast<const f32x2*>(Wi + r * 2);
        const f32x4* ur = reinterpret_cast<const f32x4*>(Wh + r * 8);
        whv[g][0] = ur[0]; whv[g][1] = ur[1];
        bsv[g] = Bs[r];
    }
#pragma unroll
    for (int g = 0; g < 4; g++) {
        asm volatile("" : "+v"(wiv[g]));
        asm volatile("" : "+v"(whv[g][0]), "+v"(whv[g][1]));
    }
    asm volatile("" : "+v"(bsv));

    float hin[8];
    {
        const f32x4* hp = reinterpret_cast<const f32x4*>(h0e);
        f32x4 a = hp[0], b = hp[1];
        hin[0] = a.x; hin[1] = a.y; hin[2] = a.z; hin[3] = a.w;
        hin[4] = b.x; hin[5] = b.y; hin[6] = b.z; hin[7] = b.w;
    }
    float cc = c0e[u];

#pragma unroll
    for (int s = 0; s < 4; s++) {
        const int t = FWD ? s : 3 - s;
        f32x2 acc[4];
#pragma unroll
        for (int g = 0; g < 4; g++) {
            acc[g] = __builtin_elementwise_fma(xin2[t], wiv[g], f32x2{bsv[g], 0.0f});
#pragma unroll
            for (int j = 0; j < 2; j++) {
                f32x2 wlo = f32x2{whv[g][j].x, whv[g][j].y};
                f32x2 whi = f32x2{whv[g][j].z, whv[g][j].w};
                f32x2 h0p = f32x2{hin[4 * j], hin[4 * j + 1]};
                f32x2 h1p = f32x2{hin[4 * j + 2], hin[4 * j + 3]};
                acc[g] = __builtin_elementwise_fma(h0p, wlo, acc[g]);
                acc[g] = __builtin_elementwise_fma(h1p, whi, acc[g]);
            }
        }
        float si = sigm(acc[0].x + acc[0].y);
        float sf = sigm(acc[1].x + acc[1].y);
        float tg = tanhx(acc[2].x + acc[2].y);
        float so = sigm(acc[3].x + acc[3].y);
        cc = fmaf(sf, cc, si * tg);
        float hn = so * tanhx(cc);
#pragma unroll
        for (int k = 0; k < 8; k++)
            hin[k] = __int_as_float(
                __builtin_amdgcn_ds_bpermute(bbase + 4 * k, __float_as_int(hn)));
        lout[16 * t + (FWD ? 0 : 8) + u] = hn;
    }
}

// ---------------------------------------------------------------------------
// main: block = 256 threads = 4 waves = 32 elems; 8 lanes per elem
// ---------------------------------------------------------------------------
__global__ __launch_bounds__(256, 2) void lstm_main(
    const float* __restrict__ x, const float* __restrict__ h0,
    const float* __restrict__ c0, const float* __restrict__ W,
    float* __restrict__ out, int B)
{
    __shared__ float yb[2][32 * 68];   // stride 68: conflict-free (see notes)
    const int tid = threadIdx.x;
    const int lane = tid & 63;
    const int u = lane & 7;
    const int eLocal = tid >> 3;                 // 0..31
    const int elem = blockIdx.x * 32 + eLocal;
    const int bbase = (lane & 56) << 2;          // bpermute byte base

    float* y0 = &yb[0][eLocal * 68];
    float* y1 = &yb[1][eLocal * 68];

    f32x2 xin2[4];
    {
        const f32x4* xp = reinterpret_cast<const f32x4*>(x + (size_t)elem * 8);
        f32x4 a = xp[0], b = xp[1];
        xin2[0] = f32x2{a.x, a.y}; xin2[1] = f32x2{a.z, a.w};
        xin2[2] = f32x2{b.x, b.y}; xin2[3] = f32x2{b.z, b.w};
    }

    // layer 0 -> y0
    layer2<true>(W + OFF_WIH0, W + OFF_WHH0, W + OFF_B0,
                 h0 + ((size_t)0 * B + elem) * 8, c0 + ((size_t)0 * B + elem) * 8,
                 u, bbase, xin2, y0);
    layer2<false>(W + OFF_WIH0 + 64, W + OFF_WHH0 + 256, W + OFF_B0 + 32,
                  h0 + ((size_t)1 * B + elem) * 8, c0 + ((size_t)1 * B + elem) * 8,
                  u, bbase, xin2, y0);

    // layers 1..5: ping-pong y0 <-> y1 (l odd: y0 -> y1)
#pragma unroll
    for (int l = 1; l <= 5; l++) {
        const float* lin = (l & 1) ? y0 : y1;
        float* lout = (l & 1) ? y1 : y0;
        const float* wi = W + OFF_WIH + (size_t)(l - 1) * 1024;
        const float* wh = W + OFF_WHH + (size_t)(l - 1) * 512;
        const float* bb = W + OFF_B + (size_t)(l - 1) * 64;
        const int slot = 2 * l;
        const bool last = (l == 5);
        layer16<true>(wi, wh, bb,
                      h0 + ((size_t)slot * B + elem) * 8,
                      c0 + ((size_t)slot * B + elem) * 8,
                      u, bbase, lin, lout, last);
        layer16<false>(wi + 512, wh + 256, bb + 32,
                       h0 + ((size_t)(slot + 1) * B + elem) * 8,
                       c0 + ((size_t)(slot + 1) * B + elem) * 8,
                       u, bbase, lin, lout, last);
    }

    // head: y1 holds sigm(s[64]); lane computes output rows 2u, 2u+1
    {
        const int o0 = 2 * u, o1 = 2 * u + 1;
        const f32x4* M0 = reinterpret_cast<const f32x4*>(W + OFF_M + o0 * 64);
        const f32x4* M1 = reinterpret_cast<const f32x4*>(W + OFF_M + o1 * 64);
        float a0 = W[OFF_MB + o0];
        float a1 = W[OFF_MB + o1];
#pragma unroll
        for (int q = 0; q < 16; q++) {
            f32x4 sv = *reinterpret_cast<const f32x4*>(y1 + 4 * q);
            f32x4 m0 = M0[q], m1 = M1[q];
            a0 = fmaf(sv.x, m0.x, a0); a0 = fmaf(sv.y, m0.y, a0);
            a0 = fmaf(sv.z, m0.z, a0); a0 = fmaf(sv.w, m0.w, a0);
            a1 = fmaf(sv.x, m1.x, a1); a1 = fmaf(sv.y, m1.y, a1);
            a1 = fmaf(sv.z, m1.z, a1); a1 = fmaf(sv.w, m1.w, a1);
        }
        f32x2 res;
        res.x = tanhx(a0);
        res.y = tanhx(a1);
        *reinterpret_cast<f32x2*>(out + (size_t)elem * 16 + 2 * u) = res;
    }
}

extern "C" void kernel_launch(void* const* d_in, const int* in_sizes, int n_in,
                              void* d_out, int out_size, void* d_ws, size_t ws_size,
                              hipStream_t stream)
{
    const float* x    = (const float*)d_in[0];
    const float* h0   = (const float*)d_in[1];
    const float* c0   = (const float*)d_in[2];
    const float* wih0 = (const float*)d_in[3];
    const float* whh0 = (const float*)d_in[4];
    const float* bih0 = (const float*)d_in[5];
    const float* bhh0 = (const float*)d_in[6];
    const float* wih  = (const float*)d_in[7];
    const float* whh  = (const float*)d_in[8];
    const float* bih  = (const float*)d_in[9];
    const float* bhh  = (const float*)d_in[10];
    const float* c1w  = (const float*)d_in[11];
    const float* c1b  = (const float*)d_in[12];
    const float* c2w  = (const float*)d_in[13];
    const float* c2b  = (const float*)d_in[14];
    const float* d1w  = (const float*)d_in[15];
    const float* d1b  = (const float*)d_in[16];
    const float* d2w  = (const float*)d_in[17];
    const float* d2b  = (const float*)d_in[18];
    const float* f1w  = (const float*)d_in[19];
    const float* f1b  = (const float*)d_in[20];
    const float* f2w  = (const float*)d_in[21];
    const float* f2b  = (const float*)d_in[22];

    float* W = (float*)d_ws;
    const int B = in_sizes[0] / 8;

    prep_all<<<41, 256, 0, stream>>>(wih0, whh0, bih0, bhh0, wih, whh, bih, bhh,
                                     c1w, c1b, c2w, c2b, d1w, d1b, d2w, d2b,
                                     f1w, f1b, f2w, f2b, W);
    lstm_main<<<B / 32, 256, 0, stream>>>(x, h0, c0, W, (float*)d_out, B);
}

// Round 5
// 380.058 us; speedup vs baseline: 4.4874x; 1.1584x over previous
//
#include <hip/hip_runtime.h>
#include <hip/hip_bf16.h>

// ---------------------------------------------------------------------------
// LSTM_net: 6x biLSTM(H=8, T=4) + composed affine head, B=131072. All f32.
// Round 5: E=4 elements per lane (ILP + weight-cost amortization).
//  - lane = (slot, unit u); each lane runs unit u of FOUR batch elements
//  - weights loaded once per layer-dir, shared across the 4 elements:
//    any AGPR/L1 access cost is amortized 4x; 16 indep FMA chains hide
//    ds_bpermute (~120cyc) and transcendental latency
//  - activations in LDS ping-pong rows (stride 68), same-wave, no barriers
//  - block 128 = 2 waves = 64 elems; grid 2048
// ---------------------------------------------------------------------------

using f32x2 = __attribute__((ext_vector_type(2))) float;
using f32x4 = __attribute__((ext_vector_type(4))) float;

#define OFF_WIH0 0      // [2][32][2]   = 128
#define OFF_WHH0 128    // [2][32][8]   = 512
#define OFF_B0   640    // [2][32]      = 64   (b_ih0 + b_hh0)
#define OFF_WIH  704    // [5][2][32][16] = 5120
#define OFF_WHH  5824   // [5][2][32][8]  = 2560
#define OFF_B    8384   // [5][2][32]     = 640 (b_ih + b_hh)
#define OFF_M    9024   // [16][64]       = 1024 (composed conv head, linear)
#define OFF_MB   10048  // [16]           = 16   (composed conv head, bias)

__device__ __forceinline__ float rcpf_(float x) {
#if __has_builtin(__builtin_amdgcn_rcpf)
    return __builtin_amdgcn_rcpf(x);
#else
    return 1.0f / x;
#endif
}
__device__ __forceinline__ float exp2f_(float x) {
#if __has_builtin(__builtin_amdgcn_exp2f)
    return __builtin_amdgcn_exp2f(x);
#else
    return exp2f(x);
#endif
}
__device__ __forceinline__ float sigm(float x) {
    return rcpf_(1.0f + exp2f_(-1.44269504f * x));
}
__device__ __forceinline__ float tanhx(float x) {
    return fmaf(2.0f, rcpf_(1.0f + exp2f_(-2.88539008f * x)), -1.0f);
}

// ---------------------------------------------------------------------------
// prep (fused): blocks 0..35 repack LSTM weights; blocks 36..40 compose the
// affine conv/deconv/fc head into M[16x64] + Mb[16].  (verified rounds 2-4)
// ---------------------------------------------------------------------------
__global__ __launch_bounds__(256) void prep_all(
    const float* __restrict__ wih0, const float* __restrict__ whh0,
    const float* __restrict__ bih0, const float* __restrict__ bhh0,
    const float* __restrict__ wih,  const float* __restrict__ whh,
    const float* __restrict__ bih,  const float* __restrict__ bhh,
    const float* __restrict__ c1w, const float* __restrict__ c1b,
    const float* __restrict__ c2w, const float* __restrict__ c2b,
    const float* __restrict__ d1w, const float* __restrict__ d1b,
    const float* __restrict__ d2w, const float* __restrict__ d2b,
    const float* __restrict__ f1w, const float* __restrict__ f1b,
    const float* __restrict__ f2w, const float* __restrict__ f2b,
    float* __restrict__ W)
{
    __shared__ float A[13][232];
    __shared__ float Bf[13][232];
    const int tid = threadIdx.x;

    if (blockIdx.x < 36) {
        int t = blockIdx.x * 256 + tid;
        const int n = 36 * 256;
        for (int i = t; i < 128; i += n)  W[OFF_WIH0 + i] = wih0[i];
        for (int i = t; i < 512; i += n)  W[OFF_WHH0 + i] = whh0[i];
        for (int i = t; i < 64; i += n)   W[OFF_B0 + i] = bih0[i] + bhh0[i];
        for (int i = t; i < 5120; i += n) W[OFF_WIH + i] = wih[i];
        for (int i = t; i < 2560; i += n) W[OFF_WHH + i] = whh[i];
        for (int i = t; i < 640; i += n)  W[OFF_B + i] = bih[i] + bhh[i];
        return;
    }
    const int base = (blockIdx.x - 36) * 13;

    for (int idx = tid; idx < 13 * 64; idx += 256) {
        int cl = idx / 64, r = idx % 64;
        A[cl][r] = (base + cl == r) ? 1.0f : 0.0f;
    }
    __syncthreads();
    for (int idx = tid; idx < 13 * 120; idx += 256) {
        int cl = idx / 120, rr = idx % 120; int o = rr / 15, l = rr % 15;
        float acc = (base + cl == 64) ? c1b[o] : 0.0f;
        for (int i = 0; i < 4; i++)
            for (int kk = 0; kk < 2; kk++)
                acc += c1w[(o * 4 + i) * 2 + kk] * A[cl][i * 16 + l + kk];
        Bf[cl][rr] = acc;
    }
    __syncthreads();
    for (int idx = tid; idx < 13 * 224; idx += 256) {
        int cl = idx / 224, rr = idx % 224; int o = rr / 14, l = rr % 14;
        float acc = (base + cl == 64) ? c2b[o] : 0.0f;
        for (int i = 0; i < 8; i++)
            for (int kk = 0; kk < 2; kk++)
                acc += c2w[(o * 8 + i) * 2 + kk] * Bf[cl][i * 15 + l + kk];
        A[cl][rr] = acc;
    }
    __syncthreads();
    for (int idx = tid; idx < 13 * 120; idx += 256) {
        int cl = idx / 120, rr = idx % 120; int o = rr / 15, l = rr % 15;
        float acc = (base + cl == 64) ? d1b[o] : 0.0f;
        for (int i = 0; i < 16; i++)
            for (int kk = 0; kk < 2; kk++) {
                int ls = l - kk;
                if (ls >= 0 && ls < 14)
                    acc += d1w[(i * 8 + o) * 2 + kk] * A[cl][i * 14 + ls];
            }
        Bf[cl][rr] = acc;
    }
    __syncthreads();
    for (int idx = tid; idx < 13 * 64; idx += 256) {
        int cl = idx / 64, rr = idx % 64; int o = rr / 16, l = rr % 16;
        float acc = (base + cl == 64) ? d2b[o] : 0.0f;
        for (int i = 0; i < 8; i++)
            for (int kk = 0; kk < 2; kk++) {
                int ls = l - kk;
                if (ls >= 0 && ls < 15)
                    acc += d2w[(i * 4 + o) * 2 + kk] * Bf[cl][i * 15 + ls];
            }
        A[cl][rr] = acc;
    }
    __syncthreads();
    for (int idx = tid; idx < 13 * 32; idx += 256) {
        int cl = idx / 32, rr = idx % 32; int ch = rr / 8, jj = rr % 8;
        float acc = (base + cl == 64) ? f1b[jj] : 0.0f;
        for (int l = 0; l < 16; l++)
            acc += f1w[jj * 16 + l] * A[cl][ch * 16 + l];
        Bf[cl][rr] = acc;
    }
    __syncthreads();
    for (int idx = tid; idx < 13 * 16; idx += 256) {
        int cl = idx / 16, rr = idx % 16; int ch = rr / 4, m = rr % 4;
        int col = base + cl;
        if (col > 64) continue;
        float acc = (col == 64) ? f2b[m] : 0.0f;
        for (int j = 0; j < 8; j++)
            acc += f2w[m * 8 + j] * Bf[cl][ch * 8 + j];
        if (col < 64) W[OFF_M + rr * 64 + col] = acc;
        else          W[OFF_MB + rr] = acc;
    }
}

// ---------------------------------------------------------------------------
// one layer-direction, Din=16, E=4 elements per lane.
// ---------------------------------------------------------------------------
template<bool FWD>
__device__ __forceinline__ void layer16(
    const float* __restrict__ Wi, const float* __restrict__ Wh,
    const float* __restrict__ Bs,
    const float* __restrict__ h0s, const float* __restrict__ c0s,
    int elem0, int u, int bbase,
    float* const (&lin)[4], float* const (&lout)[4], bool last)
{
    f32x4 wiv[4][4];   // 4 gates x 16 input weights
    f32x4 whv[4][2];   // 4 gates x 8 hidden weights
    f32x4 bsv;
#pragma unroll
    for (int g = 0; g < 4; g++) {
        const int r = u + 8 * g;
        const f32x4* wr = reinterpret_cast<const f32x4*>(Wi + r * 16);
        wiv[g][0] = wr[0]; wiv[g][1] = wr[1]; wiv[g][2] = wr[2]; wiv[g][3] = wr[3];
        const f32x4* ur = reinterpret_cast<const f32x4*>(Wh + r * 8);
        whv[g][0] = ur[0]; whv[g][1] = ur[1];
        bsv[g] = Bs[r];
    }

    float hin[4][8];
    float cc[4];
#pragma unroll
    for (int e = 0; e < 4; e++) {
        const f32x4* hp = reinterpret_cast<const f32x4*>(h0s + (size_t)(elem0 + e) * 8);
        f32x4 a = hp[0], b = hp[1];
        hin[e][0] = a.x; hin[e][1] = a.y; hin[e][2] = a.z; hin[e][3] = a.w;
        hin[e][4] = b.x; hin[e][5] = b.y; hin[e][6] = b.z; hin[e][7] = b.w;
        cc[e] = c0s[(size_t)(elem0 + e) * 8 + u];
    }

#pragma unroll
    for (int s = 0; s < 4; s++) {
        const int t = FWD ? s : 3 - s;
        f32x2 acc[4][4];
        // input part: one element at a time (keeps xin live range short)
#pragma unroll
        for (int e = 0; e < 4; e++) {
            const f32x4* ip = reinterpret_cast<const f32x4*>(lin[e] + 16 * t);
            f32x4 i0 = ip[0], i1 = ip[1], i2 = ip[2], i3 = ip[3];
            f32x2 xin[8];
            xin[0] = f32x2{i0.x, i0.y}; xin[1] = f32x2{i0.z, i0.w};
            xin[2] = f32x2{i1.x, i1.y}; xin[3] = f32x2{i1.z, i1.w};
            xin[4] = f32x2{i2.x, i2.y}; xin[5] = f32x2{i2.z, i2.w};
            xin[6] = f32x2{i3.x, i3.y}; xin[7] = f32x2{i3.z, i3.w};
#pragma unroll
            for (int g = 0; g < 4; g++) {
                f32x2 a = f32x2{bsv[g], 0.0f};
#pragma unroll
                for (int j = 0; j < 4; j++) {
                    f32x2 wlo = f32x2{wiv[g][j].x, wiv[g][j].y};
                    f32x2 whi = f32x2{wiv[g][j].z, wiv[g][j].w};
                    a = __builtin_elementwise_fma(xin[2 * j], wlo, a);
                    a = __builtin_elementwise_fma(xin[2 * j + 1], whi, a);
                }
                acc[e][g] = a;
            }
        }
        // hidden part: weight pair shared across the 4 elements
#pragma unroll
        for (int g = 0; g < 4; g++) {
#pragma unroll
            for (int j = 0; j < 2; j++) {
                f32x2 wlo = f32x2{whv[g][j].x, whv[g][j].y};
                f32x2 whi = f32x2{whv[g][j].z, whv[g][j].w};
#pragma unroll
                for (int e = 0; e < 4; e++) {
                    f32x2 h0p = f32x2{hin[e][4 * j], hin[e][4 * j + 1]};
                    f32x2 h1p = f32x2{hin[e][4 * j + 2], hin[e][4 * j + 3]};
                    acc[e][g] = __builtin_elementwise_fma(h0p, wlo, acc[e][g]);
                    acc[e][g] = __builtin_elementwise_fma(h1p, whi, acc[e][g]);
                }
            }
        }
        float hn[4];
#pragma unroll
        for (int e = 0; e < 4; e++) {
            float si = sigm(acc[e][0].x + acc[e][0].y);
            float sf = sigm(acc[e][1].x + acc[e][1].y);
            float tg = tanhx(acc[e][2].x + acc[e][2].y);
            float so = sigm(acc[e][3].x + acc[e][3].y);
            cc[e] = fmaf(sf, cc[e], si * tg);
            hn[e] = so * tanhx(cc[e]);
        }
#pragma unroll
        for (int e = 0; e < 4; e++)
#pragma unroll
            for (int k = 0; k < 8; k++)
                hin[e][k] = __int_as_float(
                    __builtin_amdgcn_ds_bpermute(bbase + 4 * k, __float_as_int(hn[e])));
#pragma unroll
        for (int e = 0; e < 4; e++)
            lout[e][16 * t + (FWD ? 0 : 8) + u] = last ? sigm(hn[e]) : hn[e];
    }
}

// layer 0 (Din=2), input in registers
template<bool FWD>
__device__ __forceinline__ void layer2(
    const float* __restrict__ Wi, const float* __restrict__ Wh,
    const float* __restrict__ Bs,
    const float* __restrict__ h0s, const float* __restrict__ c0s,
    int elem0, int u, int bbase,
    const f32x2 (&xin2)[4][4], float* const (&lout)[4])
{
    f32x2 wiv[4];
    f32x4 whv[4][2];
    f32x4 bsv;
#pragma unroll
    for (int g = 0; g < 4; g++) {
        const int r = u + 8 * g;
        wiv[g] = *reinterpret_cast<const f32x2*>(Wi + r * 2);
        const f32x4* ur = reinterpret_cast<const f32x4*>(Wh + r * 8);
        whv[g][0] = ur[0]; whv[g][1] = ur[1];
        bsv[g] = Bs[r];
    }
    float hin[4][8];
    float cc[4];
#pragma unroll
    for (int e = 0; e < 4; e++) {
        const f32x4* hp = reinterpret_cast<const f32x4*>(h0s + (size_t)(elem0 + e) * 8);
        f32x4 a = hp[0], b = hp[1];
        hin[e][0] = a.x; hin[e][1] = a.y; hin[e][2] = a.z; hin[e][3] = a.w;
        hin[e][4] = b.x; hin[e][5] = b.y; hin[e][6] = b.z; hin[e][7] = b.w;
        cc[e] = c0s[(size_t)(elem0 + e) * 8 + u];
    }

#pragma unroll
    for (int s = 0; s < 4; s++) {
        const int t = FWD ? s : 3 - s;
        f32x2 acc[4][4];
#pragma unroll
        for (int e = 0; e < 4; e++)
#pragma unroll
            for (int g = 0; g < 4; g++)
                acc[e][g] = __builtin_elementwise_fma(xin2[e][t], wiv[g], f32x2{bsv[g], 0.0f});
#pragma unroll
        for (int g = 0; g < 4; g++)
#pragma unroll
            for (int j = 0; j < 2; j++) {
                f32x2 wlo = f32x2{whv[g][j].x, whv[g][j].y};
                f32x2 whi = f32x2{whv[g][j].z, whv[g][j].w};
#pragma unroll
                for (int e = 0; e < 4; e++) {
                    f32x2 h0p = f32x2{hin[e][4 * j], hin[e][4 * j + 1]};
                    f32x2 h1p = f32x2{hin[e][4 * j + 2], hin[e][4 * j + 3]};
                    acc[e][g] = __builtin_elementwise_fma(h0p, wlo, acc[e][g]);
                    acc[e][g] = __builtin_elementwise_fma(h1p, whi, acc[e][g]);
                }
            }
        float hn[4];
#pragma unroll
        for (int e = 0; e < 4; e++) {
            float si = sigm(acc[e][0].x + acc[e][0].y);
            float sf = sigm(acc[e][1].x + acc[e][1].y);
            float tg = tanhx(acc[e][2].x + acc[e][2].y);
            float so = sigm(acc[e][3].x + acc[e][3].y);
            cc[e] = fmaf(sf, cc[e], si * tg);
            hn[e] = so * tanhx(cc[e]);
        }
#pragma unroll
        for (int e = 0; e < 4; e++)
#pragma unroll
            for (int k = 0; k < 8; k++)
                hin[e][k] = __int_as_float(
                    __builtin_amdgcn_ds_bpermute(bbase + 4 * k, __float_as_int(hn[e])));
#pragma unroll
        for (int e = 0; e < 4; e++)
            lout[e][16 * t + (FWD ? 0 : 8) + u] = hn[e];
    }
}

// ---------------------------------------------------------------------------
// main: block = 128 threads = 2 waves; 8 lanes x 4 elems per slot
// ---------------------------------------------------------------------------
__global__ __launch_bounds__(128, 2) void lstm_main(
    const float* __restrict__ x, const float* __restrict__ h0,
    const float* __restrict__ c0, const float* __restrict__ W,
    float* __restrict__ out, int B)
{
    __shared__ float yb[2][64 * 68];   // ping-pong activations, stride 68
    const int tid = threadIdx.x;
    const int lane = tid & 63;
    const int u = lane & 7;
    const int slot = tid >> 3;                   // 0..15
    const int elem0 = blockIdx.x * 64 + slot * 4;
    const int bbase = (lane & 56) << 2;          // bpermute byte base

    float* y0[4]; float* y1[4];
#pragma unroll
    for (int e = 0; e < 4; e++) {
        y0[e] = &yb[0][(slot * 4 + e) * 68];
        y1[e] = &yb[1][(slot * 4 + e) * 68];
    }

    f32x2 xin2[4][4];
#pragma unroll
    for (int e = 0; e < 4; e++) {
        const f32x4* xp = reinterpret_cast<const f32x4*>(x + (size_t)(elem0 + e) * 8);
        f32x4 a = xp[0], b = xp[1];
        xin2[e][0] = f32x2{a.x, a.y}; xin2[e][1] = f32x2{a.z, a.w};
        xin2[e][2] = f32x2{b.x, b.y}; xin2[e][3] = f32x2{b.z, b.w};
    }

    // layer 0 -> y0
    layer2<true>(W + OFF_WIH0, W + OFF_WHH0, W + OFF_B0,
                 h0 + (size_t)0 * B * 8, c0 + (size_t)0 * B * 8,
                 elem0, u, bbase, xin2, y0);
    layer2<false>(W + OFF_WIH0 + 64, W + OFF_WHH0 + 256, W + OFF_B0 + 32,
                  h0 + (size_t)1 * B * 8, c0 + (size_t)1 * B * 8,
                  elem0, u, bbase, xin2, y0);

    // layers 1..5: ping-pong y0 <-> y1 (odd l: y0 -> y1); final in y1
#pragma unroll
    for (int l = 1; l <= 5; l++) {
        float* const (&lin)[4] = (l & 1) ? y0 : y1;
        float* const (&lout)[4] = (l & 1) ? y1 : y0;
        const float* wi = W + OFF_WIH + (size_t)(l - 1) * 1024;
        const float* wh = W + OFF_WHH + (size_t)(l - 1) * 512;
        const float* bb = W + OFF_B + (size_t)(l - 1) * 64;
        const int slotIdx = 2 * l;
        const bool last = (l == 5);
        layer16<true>(wi, wh, bb,
                      h0 + (size_t)slotIdx * B * 8, c0 + (size_t)slotIdx * B * 8,
                      elem0, u, bbase, lin, lout, last);
        layer16<false>(wi + 512, wh + 256, bb + 32,
                       h0 + (size_t)(slotIdx + 1) * B * 8, c0 + (size_t)(slotIdx + 1) * B * 8,
                       elem0, u, bbase, lin, lout, last);
    }

    // head: y1 holds sigm(s[64]); lane computes output rows 2u, 2u+1
    {
        const int o0 = 2 * u, o1 = 2 * u + 1;
        const f32x4* M0 = reinterpret_cast<const f32x4*>(W + OFF_M + o0 * 64);
        const f32x4* M1 = reinterpret_cast<const f32x4*>(W + OFF_M + o1 * 64);
        const float b0 = W[OFF_MB + o0];
        const float b1 = W[OFF_MB + o1];
#pragma unroll
        for (int e = 0; e < 4; e++) {
            float a0 = b0, a1 = b1;
#pragma unroll
            for (int q = 0; q < 16; q++) {
                f32x4 sv = *reinterpret_cast<const f32x4*>(y1[e] + 4 * q);
                f32x4 m0 = M0[q], m1 = M1[q];
                a0 = fmaf(sv.x, m0.x, a0); a0 = fmaf(sv.y, m0.y, a0);
                a0 = fmaf(sv.z, m0.z, a0); a0 = fmaf(sv.w, m0.w, a0);
                a1 = fmaf(sv.x, m1.x, a1); a1 = fmaf(sv.y, m1.y, a1);
                a1 = fmaf(sv.z, m1.z, a1); a1 = fmaf(sv.w, m1.w, a1);
            }
            f32x2 res;
            res.x = tanhx(a0);
            res.y = tanhx(a1);
            *reinterpret_cast<f32x2*>(out + (size_t)(elem0 + e) * 16 + 2 * u) = res;
        }
    }
}

extern "C" void kernel_launch(void* const* d_in, const int* in_sizes, int n_in,
                              void* d_out, int out_size, void* d_ws, size_t ws_size,
                              hipStream_t stream)
{
    const float* x    = (const float*)d_in[0];
    const float* h0   = (const float*)d_in[1];
    const float* c0   = (const float*)d_in[2];
    const float* wih0 = (const float*)d_in[3];
    const float* whh0 = (const float*)d_in[4];
    const float* bih0 = (const float*)d_in[5];
    const float* bhh0 = (const float*)d_in[6];
    const float* wih  = (const float*)d_in[7];
    const float* whh  = (const float*)d_in[8];
    const float* bih  = (const float*)d_in[9];
    const float* bhh  = (const float*)d_in[10];
    const float* c1w  = (const float*)d_in[11];
    const float* c1b  = (const float*)d_in[12];
    const float* c2w  = (const float*)d_in[13];
    const float* c2b  = (const float*)d_in[14];
    const float* d1w  = (const float*)d_in[15];
    const float* d1b  = (const float*)d_in[16];
    const float* d2w  = (const float*)d_in[17];
    const float* d2b  = (const float*)d_in[18];
    const float* f1w  = (const float*)d_in[19];
    const float* f1b  = (const float*)d_in[20];
    const float* f2w  = (const float*)d_in[21];
    const float* f2b  = (const float*)d_in[22];

    float* W = (float*)d_ws;
    const int B = in_sizes[0] / 8;

    prep_all<<<41, 256, 0, stream>>>(wih0, whh0, bih0, bhh0, wih, whh, bih, bhh,
                                     c1w, c1b, c2w, c2b, d1w, d1b, d2w, d2b,
                                     f1w, f1b, f2w, f2b, W);
    lstm_main<<<B / 64, 128, 0, stream>>>(x, h0, c0, W, (float*)d_out, B);
}

// Round 6
// 350.289 us; speedup vs baseline: 4.8688x; 1.0850x over previous
//
#include <hip/hip_runtime.h>
#include <hip/hip_bf16.h>

// ---------------------------------------------------------------------------
// LSTM_net: 6x biLSTM(H=8, T=4) + composed affine head, B=131072. All f32.
// Round 6: E=2 elems/lane (no spills), h-propagation via LDS store+readback
// (replaces 8 ds_bpermute/step with 2 ds_read_b128 from the output row),
// block=256 (4 waves, 64 elems) for LDS-amortized occupancy.
// ---------------------------------------------------------------------------

using f32x2 = __attribute__((ext_vector_type(2))) float;
using f32x4 = __attribute__((ext_vector_type(4))) float;

#define OFF_WIH0 0      // [2][32][2]   = 128
#define OFF_WHH0 128    // [2][32][8]   = 512
#define OFF_B0   640    // [2][32]      = 64   (b_ih0 + b_hh0)
#define OFF_WIH  704    // [5][2][32][16] = 5120
#define OFF_WHH  5824   // [5][2][32][8]  = 2560
#define OFF_B    8384   // [5][2][32]     = 640 (b_ih + b_hh)
#define OFF_M    9024   // [16][64]       = 1024 (composed conv head, linear)
#define OFF_MB   10048  // [16]           = 16   (composed conv head, bias)

__device__ __forceinline__ float rcpf_(float x) {
#if __has_builtin(__builtin_amdgcn_rcpf)
    return __builtin_amdgcn_rcpf(x);
#else
    return 1.0f / x;
#endif
}
__device__ __forceinline__ float exp2f_(float x) {
#if __has_builtin(__builtin_amdgcn_exp2f)
    return __builtin_amdgcn_exp2f(x);
#else
    return exp2f(x);
#endif
}
__device__ __forceinline__ float sigm(float x) {
    return rcpf_(1.0f + exp2f_(-1.44269504f * x));
}
__device__ __forceinline__ float tanhx(float x) {
    return fmaf(2.0f, rcpf_(1.0f + exp2f_(-2.88539008f * x)), -1.0f);
}

// ---------------------------------------------------------------------------
// prep (fused): blocks 0..35 repack LSTM weights; blocks 36..40 compose the
// affine conv/deconv/fc head into M[16x64] + Mb[16].  (verified rounds 2-5)
// ---------------------------------------------------------------------------
__global__ __launch_bounds__(256) void prep_all(
    const float* __restrict__ wih0, const float* __restrict__ whh0,
    const float* __restrict__ bih0, const float* __restrict__ bhh0,
    const float* __restrict__ wih,  const float* __restrict__ whh,
    const float* __restrict__ bih,  const float* __restrict__ bhh,
    const float* __restrict__ c1w, const float* __restrict__ c1b,
    const float* __restrict__ c2w, const float* __restrict__ c2b,
    const float* __restrict__ d1w, const float* __restrict__ d1b,
    const float* __restrict__ d2w, const float* __restrict__ d2b,
    const float* __restrict__ f1w, const float* __restrict__ f1b,
    const float* __restrict__ f2w, const float* __restrict__ f2b,
    float* __restrict__ W)
{
    __shared__ float A[13][232];
    __shared__ float Bf[13][232];
    const int tid = threadIdx.x;

    if (blockIdx.x < 36) {
        int t = blockIdx.x * 256 + tid;
        const int n = 36 * 256;
        for (int i = t; i < 128; i += n)  W[OFF_WIH0 + i] = wih0[i];
        for (int i = t; i < 512; i += n)  W[OFF_WHH0 + i] = whh0[i];
        for (int i = t; i < 64; i += n)   W[OFF_B0 + i] = bih0[i] + bhh0[i];
        for (int i = t; i < 5120; i += n) W[OFF_WIH + i] = wih[i];
        for (int i = t; i < 2560; i += n) W[OFF_WHH + i] = whh[i];
        for (int i = t; i < 640; i += n)  W[OFF_B + i] = bih[i] + bhh[i];
        return;
    }
    const int base = (blockIdx.x - 36) * 13;

    for (int idx = tid; idx < 13 * 64; idx += 256) {
        int cl = idx / 64, r = idx % 64;
        A[cl][r] = (base + cl == r) ? 1.0f : 0.0f;
    }
    __syncthreads();
    for (int idx = tid; idx < 13 * 120; idx += 256) {
        int cl = idx / 120, rr = idx % 120; int o = rr / 15, l = rr % 15;
        float acc = (base + cl == 64) ? c1b[o] : 0.0f;
        for (int i = 0; i < 4; i++)
            for (int kk = 0; kk < 2; kk++)
                acc += c1w[(o * 4 + i) * 2 + kk] * A[cl][i * 16 + l + kk];
        Bf[cl][rr] = acc;
    }
    __syncthreads();
    for (int idx = tid; idx < 13 * 224; idx += 256) {
        int cl = idx / 224, rr = idx % 224; int o = rr / 14, l = rr % 14;
        float acc = (base + cl == 64) ? c2b[o] : 0.0f;
        for (int i = 0; i < 8; i++)
            for (int kk = 0; kk < 2; kk++)
                acc += c2w[(o * 8 + i) * 2 + kk] * Bf[cl][i * 15 + l + kk];
        A[cl][rr] = acc;
    }
    __syncthreads();
    for (int idx = tid; idx < 13 * 120; idx += 256) {
        int cl = idx / 120, rr = idx % 120; int o = rr / 15, l = rr % 15;
        float acc = (base + cl == 64) ? d1b[o] : 0.0f;
        for (int i = 0; i < 16; i++)
            for (int kk = 0; kk < 2; kk++) {
                int ls = l - kk;
                if (ls >= 0 && ls < 14)
                    acc += d1w[(i * 8 + o) * 2 + kk] * A[cl][i * 14 + ls];
            }
        Bf[cl][rr] = acc;
    }
    __syncthreads();
    for (int idx = tid; idx < 13 * 64; idx += 256) {
        int cl = idx / 64, rr = idx % 64; int o = rr / 16, l = rr % 16;
        float acc = (base + cl == 64) ? d2b[o] : 0.0f;
        for (int i = 0; i < 8; i++)
            for (int kk = 0; kk < 2; kk++) {
                int ls = l - kk;
                if (ls >= 0 && ls < 15)
                    acc += d2w[(i * 4 + o) * 2 + kk] * Bf[cl][i * 15 + ls];
            }
        A[cl][rr] = acc;
    }
    __syncthreads();
    for (int idx = tid; idx < 13 * 32; idx += 256) {
        int cl = idx / 32, rr = idx % 32; int ch = rr / 8, jj = rr % 8;
        float acc = (base + cl == 64) ? f1b[jj] : 0.0f;
        for (int l = 0; l < 16; l++)
            acc += f1w[jj * 16 + l] * A[cl][ch * 16 + l];
        Bf[cl][rr] = acc;
    }
    __syncthreads();
    for (int idx = tid; idx < 13 * 16; idx += 256) {
        int cl = idx / 16, rr = idx % 16; int ch = rr / 4, m = rr % 4;
        int col = base + cl;
        if (col > 64) continue;
        float acc = (col == 64) ? f2b[m] : 0.0f;
        for (int j = 0; j < 8; j++)
            acc += f2w[m * 8 + j] * Bf[cl][ch * 8 + j];
        if (col < 64) W[OFF_M + rr * 64 + col] = acc;
        else          W[OFF_MB + rr] = acc;
    }
}

// ---------------------------------------------------------------------------
// one layer-direction, Din=16, E=2 elems per lane.
// h propagation: store hn raw into lout row; next step reads h[8] back as
// 2x ds_read_b128 (same wave, broadcast across the elem's 8 lanes).
// LAST: keep hn in regs, rewrite sigm(hn) after the loop (head input).
// ---------------------------------------------------------------------------
template<bool FWD, bool LAST>
__device__ __forceinline__ void layer16(
    const float* __restrict__ Wi, const float* __restrict__ Wh,
    const float* __restrict__ Bs,
    const float* __restrict__ h0s, const float* __restrict__ c0s,
    int gelem0, int u,
    float* const (&lin)[2], float* const (&lout)[2])
{
    f32x4 wiv[4][4];   // 4 gates x 16 input weights
    f32x4 whv[4][2];   // 4 gates x 8 hidden weights
    f32x4 bsv;
#pragma unroll
    for (int g = 0; g < 4; g++) {
        const int r = u + 8 * g;
        const f32x4* wr = reinterpret_cast<const f32x4*>(Wi + r * 16);
        wiv[g][0] = wr[0]; wiv[g][1] = wr[1]; wiv[g][2] = wr[2]; wiv[g][3] = wr[3];
        const f32x4* ur = reinterpret_cast<const f32x4*>(Wh + r * 8);
        whv[g][0] = ur[0]; whv[g][1] = ur[1];
        bsv[g] = Bs[r];
    }
    f32x4 hg[2][2];
    float cc[2];
#pragma unroll
    for (int e = 0; e < 2; e++) {
        const f32x4* hp = reinterpret_cast<const f32x4*>(h0s + (size_t)(gelem0 + e) * 8);
        hg[e][0] = hp[0]; hg[e][1] = hp[1];
        cc[e] = c0s[(size_t)(gelem0 + e) * 8 + u];
    }
    float hreg[2][4];
    const int off = FWD ? 0 : 8;

#pragma unroll
    for (int s = 0; s < 4; s++) {
        const int t = FWD ? s : 3 - s;
        const int tprev = FWD ? t - 1 : t + 1;
        f32x2 acc[2][4];
#pragma unroll
        for (int e = 0; e < 2; e++) {
            const f32x4* ip = reinterpret_cast<const f32x4*>(lin[e] + 16 * t);
            f32x4 i0 = ip[0], i1 = ip[1], i2 = ip[2], i3 = ip[3];
            f32x4 ha, hb;
            if (s == 0) { ha = hg[e][0]; hb = hg[e][1]; }
            else {
                const f32x4* hp = reinterpret_cast<const f32x4*>(lout[e] + 16 * tprev + off);
                ha = hp[0]; hb = hp[1];
            }
            f32x2 xin[8];
            xin[0] = f32x2{i0.x, i0.y}; xin[1] = f32x2{i0.z, i0.w};
            xin[2] = f32x2{i1.x, i1.y}; xin[3] = f32x2{i1.z, i1.w};
            xin[4] = f32x2{i2.x, i2.y}; xin[5] = f32x2{i2.z, i2.w};
            xin[6] = f32x2{i3.x, i3.y}; xin[7] = f32x2{i3.z, i3.w};
            f32x2 hx[4];
            hx[0] = f32x2{ha.x, ha.y}; hx[1] = f32x2{ha.z, ha.w};
            hx[2] = f32x2{hb.x, hb.y}; hx[3] = f32x2{hb.z, hb.w};
#pragma unroll
            for (int g = 0; g < 4; g++) {
                f32x2 a = f32x2{bsv[g], 0.0f};
#pragma unroll
                for (int j = 0; j < 4; j++) {
                    f32x2 wlo = f32x2{wiv[g][j].x, wiv[g][j].y};
                    f32x2 whi = f32x2{wiv[g][j].z, wiv[g][j].w};
                    a = __builtin_elementwise_fma(xin[2 * j], wlo, a);
                    a = __builtin_elementwise_fma(xin[2 * j + 1], whi, a);
                }
#pragma unroll
                for (int j = 0; j < 2; j++) {
                    f32x2 wlo = f32x2{whv[g][j].x, whv[g][j].y};
                    f32x2 whi = f32x2{whv[g][j].z, whv[g][j].w};
                    a = __builtin_elementwise_fma(hx[2 * j], wlo, a);
                    a = __builtin_elementwise_fma(hx[2 * j + 1], whi, a);
                }
                acc[e][g] = a;
            }
        }
#pragma unroll
        for (int e = 0; e < 2; e++) {
            float si = sigm(acc[e][0].x + acc[e][0].y);
            float sf = sigm(acc[e][1].x + acc[e][1].y);
            float tg = tanhx(acc[e][2].x + acc[e][2].y);
            float so = sigm(acc[e][3].x + acc[e][3].y);
            cc[e] = fmaf(sf, cc[e], si * tg);
            float hn = so * tanhx(cc[e]);
            lout[e][16 * t + off + u] = hn;
            if (LAST) hreg[e][s] = hn;
        }
    }
    if (LAST) {
#pragma unroll
        for (int e = 0; e < 2; e++)
#pragma unroll
            for (int s = 0; s < 4; s++) {
                const int t = FWD ? s : 3 - s;
                lout[e][16 * t + off + u] = sigm(hreg[e][s]);
            }
    }
}

// layer 0 (Din=2), input in registers
template<bool FWD>
__device__ __forceinline__ void layer2(
    const float* __restrict__ Wi, const float* __restrict__ Wh,
    const float* __restrict__ Bs,
    const float* __restrict__ h0s, const float* __restrict__ c0s,
    int gelem0, int u,
    const f32x2 (&xin2)[2][4], float* const (&lout)[2])
{
    f32x2 wiv[4];
    f32x4 whv[4][2];
    f32x4 bsv;
#pragma unroll
    for (int g = 0; g < 4; g++) {
        const int r = u + 8 * g;
        wiv[g] = *reinterpret_cast<const f32x2*>(Wi + r * 2);
        const f32x4* ur = reinterpret_cast<const f32x4*>(Wh + r * 8);
        whv[g][0] = ur[0]; whv[g][1] = ur[1];
        bsv[g] = Bs[r];
    }
    f32x4 hg[2][2];
    float cc[2];
#pragma unroll
    for (int e = 0; e < 2; e++) {
        const f32x4* hp = reinterpret_cast<const f32x4*>(h0s + (size_t)(gelem0 + e) * 8);
        hg[e][0] = hp[0]; hg[e][1] = hp[1];
        cc[e] = c0s[(size_t)(gelem0 + e) * 8 + u];
    }
    const int off = FWD ? 0 : 8;

#pragma unroll
    for (int s = 0; s < 4; s++) {
        const int t = FWD ? s : 3 - s;
        const int tprev = FWD ? t - 1 : t + 1;
        f32x2 acc[2][4];
#pragma unroll
        for (int e = 0; e < 2; e++) {
            f32x4 ha, hb;
            if (s == 0) { ha = hg[e][0]; hb = hg[e][1]; }
            else {
                const f32x4* hp = reinterpret_cast<const f32x4*>(lout[e] + 16 * tprev + off);
                ha = hp[0]; hb = hp[1];
            }
            f32x2 hx[4];
            hx[0] = f32x2{ha.x, ha.y}; hx[1] = f32x2{ha.z, ha.w};
            hx[2] = f32x2{hb.x, hb.y}; hx[3] = f32x2{hb.z, hb.w};
#pragma unroll
            for (int g = 0; g < 4; g++) {
                f32x2 a = __builtin_elementwise_fma(xin2[e][t], wiv[g], f32x2{bsv[g], 0.0f});
#pragma unroll
                for (int j = 0; j < 2; j++) {
                    f32x2 wlo = f32x2{whv[g][j].x, whv[g][j].y};
                    f32x2 whi = f32x2{whv[g][j].z, whv[g][j].w};
                    a = __builtin_elementwise_fma(hx[2 * j], wlo, a);
                    a = __builtin_elementwise_fma(hx[2 * j + 1], whi, a);
                }
                acc[e][g] = a;
            }
        }
#pragma unroll
        for (int e = 0; e < 2; e++) {
            float si = sigm(acc[e][0].x + acc[e][0].y);
            float sf = sigm(acc[e][1].x + acc[e][1].y);
            float tg = tanhx(acc[e][2].x + acc[e][2].y);
            float so = sigm(acc[e][3].x + acc[e][3].y);
            cc[e] = fmaf(sf, cc[e], si * tg);
            lout[e][16 * t + off + u] = so * tanhx(cc[e]);
        }
    }
}

// ---------------------------------------------------------------------------
// main: block = 256 threads = 4 waves = 64 elems; 8 lanes x E=2 per slot
// ---------------------------------------------------------------------------
__global__ __launch_bounds__(256, 3) void lstm_main(
    const float* __restrict__ x, const float* __restrict__ h0,
    const float* __restrict__ c0, const float* __restrict__ W,
    float* __restrict__ out, int B)
{
    __shared__ float yb[2][64 * 68];   // ping-pong activations, stride 68
    const int tid = threadIdx.x;
    const int u = tid & 7;
    const int slot = tid >> 3;                   // 0..31 (4 per wave-slot group)
    const int row0 = slot * 2;                   // local elem rows
    const int gelem0 = blockIdx.x * 64 + row0;

    float* y0[2]; float* y1[2];
#pragma unroll
    for (int e = 0; e < 2; e++) {
        y0[e] = &yb[0][(row0 + e) * 68];
        y1[e] = &yb[1][(row0 + e) * 68];
    }

    f32x2 xin2[2][4];
#pragma unroll
    for (int e = 0; e < 2; e++) {
        const f32x4* xp = reinterpret_cast<const f32x4*>(x + (size_t)(gelem0 + e) * 8);
        f32x4 a = xp[0], b = xp[1];
        xin2[e][0] = f32x2{a.x, a.y}; xin2[e][1] = f32x2{a.z, a.w};
        xin2[e][2] = f32x2{b.x, b.y}; xin2[e][3] = f32x2{b.z, b.w};
    }

    // layer 0 -> y0
    layer2<true>(W + OFF_WIH0, W + OFF_WHH0, W + OFF_B0,
                 h0 + (size_t)0 * B * 8, c0 + (size_t)0 * B * 8,
                 gelem0, u, xin2, y0);
    layer2<false>(W + OFF_WIH0 + 64, W + OFF_WHH0 + 256, W + OFF_B0 + 32,
                  h0 + (size_t)1 * B * 8, c0 + (size_t)1 * B * 8,
                  gelem0, u, xin2, y0);

    // layers 1..4: ping-pong; layer 5 writes sigm() into y1 for the head
#pragma unroll
    for (int l = 1; l <= 4; l++) {
        float* const (&lin)[2] = (l & 1) ? y0 : y1;
        float* const (&lout)[2] = (l & 1) ? y1 : y0;
        const float* wi = W + OFF_WIH + (size_t)(l - 1) * 1024;
        const float* wh = W + OFF_WHH + (size_t)(l - 1) * 512;
        const float* bb = W + OFF_B + (size_t)(l - 1) * 64;
        const int si = 2 * l;
        layer16<true, false>(wi, wh, bb,
                             h0 + (size_t)si * B * 8, c0 + (size_t)si * B * 8,
                             gelem0, u, lin, lout);
        layer16<false, false>(wi + 512, wh + 256, bb + 32,
                              h0 + (size_t)(si + 1) * B * 8, c0 + (size_t)(si + 1) * B * 8,
                              gelem0, u, lin, lout);
    }
    {
        const float* wi = W + OFF_WIH + (size_t)4 * 1024;
        const float* wh = W + OFF_WHH + (size_t)4 * 512;
        const float* bb = W + OFF_B + (size_t)4 * 64;
        layer16<true, true>(wi, wh, bb,
                            h0 + (size_t)10 * B * 8, c0 + (size_t)10 * B * 8,
                            gelem0, u, y0, y1);
        layer16<false, true>(wi + 512, wh + 256, bb + 32,
                             h0 + (size_t)11 * B * 8, c0 + (size_t)11 * B * 8,
                             gelem0, u, y0, y1);
    }

    // head: y1 holds sigm(s[64]); lane computes output rows 2u, 2u+1
    {
        const int o0 = 2 * u, o1 = 2 * u + 1;
        const f32x4* M0 = reinterpret_cast<const f32x4*>(W + OFF_M + o0 * 64);
        const f32x4* M1 = reinterpret_cast<const f32x4*>(W + OFF_M + o1 * 64);
        const float b0 = W[OFF_MB + o0];
        const float b1 = W[OFF_MB + o1];
#pragma unroll
        for (int e = 0; e < 2; e++) {
            float a0 = b0, a1 = b1;
#pragma unroll
            for (int q = 0; q < 16; q++) {
                f32x4 sv = *reinterpret_cast<const f32x4*>(y1[e] + 4 * q);
                f32x4 m0 = M0[q], m1 = M1[q];
                a0 = fmaf(sv.x, m0.x, a0); a0 = fmaf(sv.y, m0.y, a0);
                a0 = fmaf(sv.z, m0.z, a0); a0 = fmaf(sv.w, m0.w, a0);
                a1 = fmaf(sv.x, m1.x, a1); a1 = fmaf(sv.y, m1.y, a1);
                a1 = fmaf(sv.z, m1.z, a1); a1 = fmaf(sv.w, m1.w, a1);
            }
            f32x2 res;
            res.x = tanhx(a0);
            res.y = tanhx(a1);
            *reinterpret_cast<f32x2*>(out + (size_t)(gelem0 + e) * 16 + 2 * u) = res;
        }
    }
}

extern "C" void kernel_launch(void* const* d_in, const int* in_sizes, int n_in,
                              void* d_out, int out_size, void* d_ws, size_t ws_size,
                              hipStream_t stream)
{
    const float* x    = (const float*)d_in[0];
    const float* h0   = (const float*)d_in[1];
    const float* c0   = (const float*)d_in[2];
    const float* wih0 = (const float*)d_in[3];
    const float* whh0 = (const float*)d_in[4];
    const float* bih0 = (const float*)d_in[5];
    const float* bhh0 = (const float*)d_in[6];
    const float* wih  = (const float*)d_in[7];
    const float* whh  = (const float*)d_in[8];
    const float* bih  = (const float*)d_in[9];
    const float* bhh  = (const float*)d_in[10];
    const float* c1w  = (const float*)d_in[11];
    const float* c1b  = (const float*)d_in[12];
    const float* c2w  = (const float*)d_in[13];
    const float* c2b  = (const float*)d_in[14];
    const float* d1w  = (const float*)d_in[15];
    const float* d1b  = (const float*)d_in[16];
    const float* d2w  = (const float*)d_in[17];
    const float* d2b  = (const float*)d_in[18];
    const float* f1w  = (const float*)d_in[19];
    const float* f1b  = (const float*)d_in[20];
    const float* f2w  = (const float*)d_in[21];
    const float* f2b  = (const float*)d_in[22];

    float* W = (float*)d_ws;
    const int B = in_sizes[0] / 8;

    prep_all<<<41, 256, 0, stream>>>(wih0, whh0, bih0, bhh0, wih, whh, bih, bhh,
                                     c1w, c1b, c2w, c2b, d1w, d1b, d2w, d2b,
                                     f1w, f1b, f2w, f2b, W);
    lstm_main<<<B / 64, 256, 0, stream>>>(x, h0, c0, W, (float*)d_out, B);
}